// Round 1
// baseline (2758.715 us; speedup 1.0000x reference)
//
#include <hip/hip_runtime.h>

#define kB 4
#define kC 512
#define kCr 8
#define kH 96
#define kW 96
#define kHW (kH * kW)          // 9216
#define kCHW (kC * kHW)        // 4718592
#define NEGV -1e9f

// ---------------- small convs: f_hei, f_wid [B,8,H,W] ----------------
__global__ __launch_bounds__(256) void k_conv_small(
    const float* __restrict__ x,
    const float* __restrict__ w_h, const float* __restrict__ b_h,
    const float* __restrict__ w_w, const float* __restrict__ b_w,
    float* __restrict__ f_hei, float* __restrict__ f_wid) {
  __shared__ float wh_s[kCr * kC];
  __shared__ float ww_s[kCr * kC];
  int tid = threadIdx.x;
  for (int l = tid; l < kCr * kC; l += 256) {
    wh_s[l] = w_h[l];
    ww_s[l] = w_w[l];
  }
  __syncthreads();
  int g = blockIdx.x * 256 + tid;
  int b = g / kHW, hw = g % kHW;
  float accH[kCr] = {0.f}, accW[kCr] = {0.f};
  const float* xb = x + (size_t)b * kCHW + hw;
  for (int c = 0; c < kC; c++) {
    float xv = xb[(size_t)c * kHW];
#pragma unroll
    for (int r = 0; r < kCr; r++) {
      accH[r] += wh_s[r * kC + c] * xv;
      accW[r] += ww_s[r * kC + c] * xv;
    }
  }
#pragma unroll
  for (int r = 0; r < kCr; r++) {
    f_hei[((size_t)b * kCr + r) * kHW + hw] = accH[r] + b_h[r];
    f_wid[((size_t)b * kCr + r) * kHW + hw] = accW[r] + b_w[r];
  }
}

// ---------------- big conv1x1 as GEMM: Out[b,o,n] = sum_c W[o,c] X[b,c,n] + bias[o]
// M=512 (o), N=9216 (n), K=512. BM=BN=128, BK=16, 256 thr, 8x8 micro.
__global__ __launch_bounds__(256) void k_gemm_conv(
    const float* __restrict__ Wm, const float* __restrict__ bias,
    const float* __restrict__ X, float* __restrict__ Out) {
  int b = blockIdx.z;
  int bm = blockIdx.y * 128;
  int bn = blockIdx.x * 128;
  const float* Xb = X + (size_t)b * kCHW;
  float* Ob = Out + (size_t)b * kCHW;
  __shared__ float As[16][129];
  __shared__ float Bs[16][129];
  int tid = threadIdx.x;
  int tx = tid & 15, ty = tid >> 4;
  float acc[8][8] = {{0.f}};
  for (int k0 = 0; k0 < kC; k0 += 16) {
#pragma unroll
    for (int t = 0; t < 8; t++) {
      int l = tid + t * 256;
      int m = l >> 4, k = l & 15;
      As[k][m] = Wm[(bm + m) * kC + k0 + k];
    }
#pragma unroll
    for (int t = 0; t < 8; t++) {
      int l = tid + t * 256;
      int k = l >> 7, n = l & 127;
      Bs[k][n] = Xb[(size_t)(k0 + k) * kHW + bn + n];
    }
    __syncthreads();
#pragma unroll
    for (int k = 0; k < 16; k++) {
      float a[8], bb[8];
#pragma unroll
      for (int i = 0; i < 8; i++) a[i] = As[k][ty * 8 + i];
#pragma unroll
      for (int j = 0; j < 8; j++) bb[j] = Bs[k][tx * 8 + j];
#pragma unroll
      for (int i = 0; i < 8; i++)
#pragma unroll
        for (int j = 0; j < 8; j++) acc[i][j] += a[i] * bb[j];
    }
    __syncthreads();
  }
#pragma unroll
  for (int i = 0; i < 8; i++) {
    int m = bm + ty * 8 + i;
    float bv = bias[m];
#pragma unroll
    for (int j = 0; j < 8; j++)
      Ob[(size_t)m * kHW + bn + tx * 8 + j] = acc[i][j] + bv;
  }
}

// ---------------- Gram: G[b,i,j] = sum_n F[b,i,n] F[b,j,n]. M=N=512, K=9216.
// BM=BN=64, BK=32, 256 thr, 4x4 micro.
__global__ __launch_bounds__(256) void k_gram(
    const float* __restrict__ F, float* __restrict__ G) {
  int b = blockIdx.z;
  int bm = blockIdx.y * 64;
  int bn = blockIdx.x * 64;
  const float* Fb = F + (size_t)b * kCHW;
  __shared__ float As[32][65];
  __shared__ float Bs[32][65];
  int tid = threadIdx.x;
  int tx = tid & 15, ty = tid >> 4;
  float acc[4][4] = {{0.f}};
  for (int k0 = 0; k0 < kHW; k0 += 32) {
#pragma unroll
    for (int t = 0; t < 8; t++) {
      int l = tid + t * 256;          // 2048 = 64m x 32k
      int m = l >> 5, k = l & 31;
      As[k][m] = Fb[(size_t)(bm + m) * kHW + k0 + k];
      Bs[k][m] = Fb[(size_t)(bn + m) * kHW + k0 + k];
    }
    __syncthreads();
#pragma unroll
    for (int k = 0; k < 32; k++) {
      float a[4], bb[4];
#pragma unroll
      for (int i = 0; i < 4; i++) a[i] = As[k][ty * 4 + i];
#pragma unroll
      for (int j = 0; j < 4; j++) bb[j] = Bs[k][tx * 4 + j];
#pragma unroll
      for (int i = 0; i < 4; i++)
#pragma unroll
        for (int j = 0; j < 4; j++) acc[i][j] += a[i] * bb[j];
    }
    __syncthreads();
  }
#pragma unroll
  for (int i = 0; i < 4; i++)
#pragma unroll
    for (int j = 0; j < 4; j++)
      G[((size_t)b * kC + bm + ty * 4 + i) * kC + bn + tx * 4 + j] = acc[i][j];
}

// ---------------- row softmax over 512 (in-place), rows = B*512
__global__ __launch_bounds__(256) void k_softmax512(float* __restrict__ G) {
  size_t row = blockIdx.x;
  float* R = G + row * kC;
  int tid = threadIdx.x;
  int wid = tid >> 6, lane = tid & 63;
  float v0 = R[tid], v1 = R[tid + 256];
  float m = fmaxf(v0, v1);
#pragma unroll
  for (int o = 32; o >= 1; o >>= 1) m = fmaxf(m, __shfl_xor(m, o));
  __shared__ float redm[4];
  __shared__ float reds[4];
  if (lane == 0) redm[wid] = m;
  __syncthreads();
  m = fmaxf(fmaxf(redm[0], redm[1]), fmaxf(redm[2], redm[3]));
  float e0 = expf(v0 - m), e1 = expf(v1 - m);
  float s = e0 + e1;
#pragma unroll
  for (int o = 32; o >= 1; o >>= 1) s += __shfl_xor(s, o);
  if (lane == 0) reds[wid] = s;
  __syncthreads();
  s = reds[0] + reds[1] + reds[2] + reds[3];
  float inv = 1.0f / s;
  R[tid] = e0 * inv;
  R[tid + 256] = e1 * inv;
}

// ---------------- out_C GEMM, written scaled directly into d_out (flat-layout identity):
// Out[b*CHW + hw*512 + c] = gamma * sum_j F[b,j,hw] * aff[b,j,c]
// M=9216 (hw), N=512 (c), K=512. BM=BN=128, BK=16, 8x8 micro.
__global__ __launch_bounds__(256) void k_outc(
    const float* __restrict__ F, const float* __restrict__ aff,
    const float* __restrict__ gamma, float* __restrict__ Out) {
  int b = blockIdx.z;
  int bm = blockIdx.y * 128;  // hw
  int bn = blockIdx.x * 128;  // c
  const float* Fb = F + (size_t)b * kCHW;
  const float* Ab = aff + (size_t)b * kC * kC;
  float* Ob = Out + (size_t)b * kCHW;
  __shared__ float As[16][129];
  __shared__ float Bs[16][129];
  int tid = threadIdx.x;
  int tx = tid & 15, ty = tid >> 4;
  float g = *gamma;
  float acc[8][8] = {{0.f}};
  for (int k0 = 0; k0 < kC; k0 += 16) {
#pragma unroll
    for (int t = 0; t < 8; t++) {
      int l = tid + t * 256;
      int k = l >> 7, i = l & 127;
      As[k][i] = Fb[(size_t)(k0 + k) * kHW + bm + i];
      Bs[k][i] = Ab[(k0 + k) * kC + bn + i];
    }
    __syncthreads();
#pragma unroll
    for (int k = 0; k < 16; k++) {
      float a[8], bb[8];
#pragma unroll
      for (int i = 0; i < 8; i++) a[i] = As[k][ty * 8 + i];
#pragma unroll
      for (int j = 0; j < 8; j++) bb[j] = Bs[k][tx * 8 + j];
#pragma unroll
      for (int i = 0; i < 8; i++)
#pragma unroll
        for (int j = 0; j < 8; j++) acc[i][j] += a[i] * bb[j];
    }
    __syncthreads();
  }
#pragma unroll
  for (int i = 0; i < 8; i++) {
    int m = bm + ty * 8 + i;
#pragma unroll
    for (int j = 0; j < 8; j++)
      Ob[(size_t)m * kC + bn + tx * 8 + j] = g * acc[i][j];
  }
}

// ---------------- E_h -> concate[b,i,w, j<96]
// E_h[bw,i,j] = sum_c f_hei[b, i&7, c*12+(i>>3), w] * f_wid[b,c,j,w]  (+NEG at i==j)
__global__ __launch_bounds__(256) void k_eh(
    const float* __restrict__ fhei, const float* __restrict__ fwid,
    float* __restrict__ Ccat) {
  int b = blockIdx.x / kW, w = blockIdx.x % kW;
  __shared__ float fh[kH][kCr];
  __shared__ float fw[kCr][kH];
  int tid = threadIdx.x;
  for (int l = tid; l < kH * kCr; l += 256) {
    int i = l >> 3, c = l & 7;
    fh[i][c] = fhei[((size_t)b * kCr + (i & 7)) * kHW + (c * 12 + (i >> 3)) * kW + w];
    int c2 = l / kH, j = l % kH;
    fw[c2][j] = fwid[((size_t)b * kCr + c2) * kHW + j * kW + w];
  }
  __syncthreads();
  for (int t = tid; t < kH * kH; t += 256) {
    int i = t / kH, j = t % kH;
    float e = 0.f;
#pragma unroll
    for (int c = 0; c < kCr; c++) e += fh[i][c] * fw[c][j];
    if (i == j) e += NEGV;
    Ccat[(((size_t)b * kH + i) * kW + w) * 192 + j] = e;
  }
}

// ---------------- E_w -> concate[b,h,w, 96+j]
__global__ __launch_bounds__(256) void k_ew(
    const float* __restrict__ fhei, const float* __restrict__ fwid,
    float* __restrict__ Ccat) {
  int b = blockIdx.x / kH, h = blockIdx.x % kH;
  __shared__ float fh2[kCr][kW];
  __shared__ float fw2[kCr][kW];
  int tid = threadIdx.x;
  for (int l = tid; l < kCr * kW; l += 256) {
    int c = l / kW, w = l % kW;
    fh2[c][w] = fhei[((size_t)b * kCr + c) * kHW + h * kW + w];
    fw2[c][w] = fwid[((size_t)b * kCr + c) * kHW + h * kW + w];
  }
  __syncthreads();
  for (int t = tid; t < kW * kW; t += 256) {
    int w = t / kW, j = t % kW;
    float e = 0.f;
#pragma unroll
    for (int c = 0; c < kCr; c++) e += fh2[c][w] * fw2[c][j];
    Ccat[(((size_t)b * kH + h) * kW + w) * 192 + 96 + j] = e;
  }
}

// ---------------- softmax over 192 (in-place), one wave per row
__global__ __launch_bounds__(256) void k_softmax192(float* __restrict__ Ccat) {
  int r = blockIdx.x * 4 + (threadIdx.x >> 6);
  int lane = threadIdx.x & 63;
  float* R = Ccat + (size_t)r * 192;
  float a = R[lane], b = R[lane + 64], c = R[lane + 128];
  float m = fmaxf(a, fmaxf(b, c));
#pragma unroll
  for (int o = 32; o >= 1; o >>= 1) m = fmaxf(m, __shfl_xor(m, o));
  float ea = expf(a - m), eb = expf(b - m), ec = expf(c - m);
  float s = ea + eb + ec;
#pragma unroll
  for (int o = 32; o >= 1; o >>= 1) s += __shfl_xor(s, o);
  float inv = 1.0f / s;
  R[lane] = ea * inv;
  R[lane + 64] = eb * inv;
  R[lane + 128] = ec * inv;
}

// ---------------- final: out = x + alpha*out_H + beta*out_W + (gamma*out_C already in out)
// out_H[b,c,h,w] = sum_j f_cha[b,c,j,w] * att[b,h,w,j]
// out_W[b,c,h,w] = sum_j f_cha[b,c,h,j] * att[b,h,w,96+j]
// grid: idx = h + 96*(wh + 2*(cs + 4*b)); block 192 = 48 w x 4 c-lanes
__global__ __launch_bounds__(192) void k_final(
    const float* __restrict__ x, const float* __restrict__ fcha,
    const float* __restrict__ Ccat,
    const float* __restrict__ alpha, const float* __restrict__ beta,
    float* __restrict__ out) {
  int idx = blockIdx.x;
  int h = idx % 96; idx /= 96;
  int wh = idx & 1; idx >>= 1;
  int cs = idx & 3; idx >>= 2;
  int b = idx;
  int tid = threadIdx.x;
  int wl = tid % 48, cl = tid / 48;
  int w = wh * 48 + wl;
  __shared__ float sAtt[48][193];
  for (int l = tid; l < 48 * 192; l += 192) {
    int ww = l / 192, j = l % 192;
    sAtt[ww][j] = Ccat[(((size_t)b * kH + h) * kW + wh * 48 + ww) * 192 + j];
  }
  __syncthreads();
  float al = *alpha, be = *beta;
  const float* fb = fcha + (size_t)b * kCHW;
  for (int i = 0; i < 32; i++) {
    int c = cs * 128 + cl * 32 + i;
    const float* pH = fb + (size_t)c * kHW + w;
    const float* pW = fb + (size_t)c * kHW + h * kW;
    float accH = 0.f, accW = 0.f;
#pragma unroll 8
    for (int j = 0; j < 96; j++) {
      accH += pH[(size_t)j * kW] * sAtt[wl][j];
      accW += pW[j] * sAtt[wl][96 + j];
    }
    size_t o = (size_t)b * kCHW + (size_t)c * kHW + h * kW + w;
    out[o] = x[o] + al * accH + be * accW + out[o];
  }
}

extern "C" void kernel_launch(void* const* d_in, const int* in_sizes, int n_in,
                              void* d_out, int out_size, void* d_ws, size_t ws_size,
                              hipStream_t stream) {
  const float* x     = (const float*)d_in[0];
  const float* w_h   = (const float*)d_in[1];
  const float* b_h   = (const float*)d_in[2];
  const float* w_w   = (const float*)d_in[3];
  const float* b_w   = (const float*)d_in[4];
  const float* w_c   = (const float*)d_in[5];
  const float* b_c   = (const float*)d_in[6];
  const float* w_o   = (const float*)d_in[7];
  const float* b_o   = (const float*)d_in[8];
  const float* alpha = (const float*)d_in[9];
  const float* beta  = (const float*)d_in[10];
  const float* gamma = (const float*)d_in[11];
  float* out = (float*)d_out;
  float* ws = (float*)d_ws;

  float* f_hei = ws;                       // 294912
  float* f_wid = f_hei + 294912;           // 294912
  float* f_ch  = f_wid + 294912;           // 18874368
  float* f_cha = f_ch + 18874368;          // 18874368
  float* gram  = f_cha + 18874368;         // 1048576
  float* ccat  = gram + 1048576;           // 7077888  (total ~186 MB)

  k_conv_small<<<144, 256, 0, stream>>>(x, w_h, b_h, w_w, b_w, f_hei, f_wid);
  k_gemm_conv<<<dim3(72, 4, 4), 256, 0, stream>>>(w_c, b_c, x, f_ch);
  k_gemm_conv<<<dim3(72, 4, 4), 256, 0, stream>>>(w_o, b_o, x, f_cha);
  k_gram<<<dim3(8, 8, 4), 256, 0, stream>>>(f_ch, gram);
  k_softmax512<<<2048, 256, 0, stream>>>(gram);
  k_outc<<<dim3(4, 72, 4), 256, 0, stream>>>(f_ch, gram, gamma, out);
  k_eh<<<384, 256, 0, stream>>>(f_hei, f_wid, ccat);
  k_ew<<<384, 256, 0, stream>>>(f_hei, f_wid, ccat);
  k_softmax192<<<9216, 256, 0, stream>>>(ccat);
  k_final<<<3072, 192, 0, stream>>>(x, f_cha, ccat, alpha, beta, out);
}

// Round 2
// 513.947 us; speedup vs baseline: 5.3677x; 5.3677x over previous
//
#include <hip/hip_runtime.h>

typedef __attribute__((ext_vector_type(8))) short short8;
typedef __attribute__((ext_vector_type(4))) float f32x4;
typedef __attribute__((ext_vector_type(4))) unsigned short us4;
typedef unsigned short u16;

#define kB 4
#define kC 512
#define kCr 8
#define kH 96
#define kW 96
#define kHW 9216
#define kCHW 4718592
#define NEGV -1e9f

__device__ __forceinline__ u16 f2b(float f) {
  union { float f; unsigned u; } v; v.f = f;
  unsigned r = v.u + 0x7fff + ((v.u >> 16) & 1);
  return (u16)(r >> 16);
}
__device__ __forceinline__ float b2f(u16 h) {
  union { unsigned u; float f; } v; v.u = ((unsigned)h) << 16;
  return v.f;
}
#define MFMA(a, b, c) __builtin_amdgcn_mfma_f32_16x16x32_bf16(a, b, c, 0, 0, 0)

// ---------- generic fp32 -> bf16 convert (n multiple of 4) ----------
__global__ __launch_bounds__(256) void k_cvt(const float* __restrict__ in,
                                             u16* __restrict__ out, int n4) {
  int stride = gridDim.x * 256;
  for (int i = blockIdx.x * 256 + threadIdx.x; i < n4; i += stride) {
    f32x4 v = ((const f32x4*)in)[i];
    us4 o;
    o[0] = f2b(v[0]); o[1] = f2b(v[1]); o[2] = f2b(v[2]); o[3] = f2b(v[3]);
    ((us4*)out)[i] = o;
  }
}

// ---------- fp32 [R][C] -> bf16 [C][R] transpose-convert, 64x64 tiles ----------
__global__ __launch_bounds__(256) void k_cvt_T(const float* __restrict__ in,
                                               u16* __restrict__ out,
                                               int R, int C) {
  const float* ib = in + (size_t)blockIdx.z * R * C;
  u16* ob = out + (size_t)blockIdx.z * R * C;
  int c0 = blockIdx.x * 64, r0 = blockIdx.y * 64;
  __shared__ u16 T[64][68];
  int tid = threadIdx.x;
#pragma unroll
  for (int p = 0; p < 4; p++) {
    int ch = tid + p * 256;
    int i = ch >> 4, seg = ch & 15;
    f32x4 v = *(const f32x4*)&ib[(size_t)(r0 + i) * C + c0 + seg * 4];
    T[i][seg*4+0] = f2b(v[0]); T[i][seg*4+1] = f2b(v[1]);
    T[i][seg*4+2] = f2b(v[2]); T[i][seg*4+3] = f2b(v[3]);
  }
  __syncthreads();
#pragma unroll
  for (int p = 0; p < 4; p++) {
    int ch = tid + p * 256;
    int j = ch >> 4, seg = ch & 15;
    us4 o;
#pragma unroll
    for (int e = 0; e < 4; e++) o[e] = T[seg*4+e][j];
    *(us4*)&ob[(size_t)(c0 + j) * R + r0 + seg * 4] = o;
  }
}

// ---------- bf16 [R][C] -> bf16 [C][R] transpose, 64x64 tiles ----------
__global__ __launch_bounds__(256) void k_trT_bf(const u16* __restrict__ in,
                                                u16* __restrict__ out,
                                                int R, int C) {
  const u16* ib = in + (size_t)blockIdx.z * R * C;
  u16* ob = out + (size_t)blockIdx.z * R * C;
  int c0 = blockIdx.x * 64, r0 = blockIdx.y * 64;
  __shared__ u16 T[64][68];
  int tid = threadIdx.x;
#pragma unroll
  for (int p = 0; p < 4; p++) {
    int ch = tid + p * 256;
    int i = ch >> 4, seg = ch & 15;
    us4 v = *(const us4*)&ib[(size_t)(r0 + i) * C + c0 + seg * 4];
    T[i][seg*4+0] = v[0]; T[i][seg*4+1] = v[1];
    T[i][seg*4+2] = v[2]; T[i][seg*4+3] = v[3];
  }
  __syncthreads();
#pragma unroll
  for (int p = 0; p < 4; p++) {
    int ch = tid + p * 256;
    int j = ch >> 4, seg = ch & 15;
    us4 o;
#pragma unroll
    for (int e = 0; e < 4; e++) o[e] = T[seg*4+e][j];
    *(us4*)&ob[(size_t)(c0 + j) * R + r0 + seg * 4] = o;
  }
}

// ---------- small convs: f_hei, f_wid [B,8,H,W] (fp32, cheap) ----------
__global__ __launch_bounds__(256) void k_conv_small(
    const float* __restrict__ x,
    const float* __restrict__ w_h, const float* __restrict__ b_h,
    const float* __restrict__ w_w, const float* __restrict__ b_w,
    float* __restrict__ f_hei, float* __restrict__ f_wid) {
  __shared__ float wh_s[kCr * kC];
  __shared__ float ww_s[kCr * kC];
  int tid = threadIdx.x;
  for (int l = tid; l < kCr * kC; l += 256) {
    wh_s[l] = w_h[l];
    ww_s[l] = w_w[l];
  }
  __syncthreads();
  int g = blockIdx.x * 256 + tid;
  int b = g / kHW, hw = g % kHW;
  float accH[kCr] = {0.f}, accW[kCr] = {0.f};
  const float* xb = x + (size_t)b * kCHW + hw;
  for (int c = 0; c < kC; c++) {
    float xv = xb[(size_t)c * kHW];
#pragma unroll
    for (int r = 0; r < kCr; r++) {
      accH[r] += wh_s[r * kC + c] * xv;
      accW[r] += ww_s[r * kC + c] * xv;
    }
  }
#pragma unroll
  for (int r = 0; r < kCr; r++) {
    f_hei[((size_t)b * kCr + r) * kHW + hw] = accH[r] + b_h[r];
    f_wid[((size_t)b * kCr + r) * kHW + hw] = accW[r] + b_w[r];
  }
}

// ---------- conv1x1 MFMA GEMM: Out[b][o][n] = sum_c W[o][c]*XT[b][n][c] + bias ----------
// A = W bf16 [512][512], B = xbfT [B][9216][512]; A.B^T; BM=BN=128, BK=64.
__global__ __launch_bounds__(256) void k_gemm_conv(
    const u16* __restrict__ A, const u16* __restrict__ BT,
    const float* __restrict__ bias, u16* __restrict__ Out) {
  int b = blockIdx.z;
  int bm = blockIdx.y * 128;   // o
  int bn = blockIdx.x * 128;   // hw
  const u16* Bb = BT + (size_t)b * kCHW;
  __shared__ u16 As[128][72];
  __shared__ u16 Bs[128][72];
  int tid = threadIdx.x;
  int lane = tid & 63, wv = tid >> 6;
  int wr = (wv >> 1) * 64, wc = (wv & 1) * 64;
  int lr = lane & 15, lg = lane >> 4;
  f32x4 acc[4][4] = {};
  for (int k0 = 0; k0 < kC; k0 += 64) {
#pragma unroll
    for (int p = 0; p < 4; p++) {
      int ch = tid + p * 256;
      int row = ch >> 3, seg = ch & 7;
      *(short8*)&As[row][seg*8] = *(const short8*)&A[(size_t)(bm+row)*512 + k0 + seg*8];
      *(short8*)&Bs[row][seg*8] = *(const short8*)&Bb[(size_t)(bn+row)*512 + k0 + seg*8];
    }
    __syncthreads();
#pragma unroll
    for (int ks = 0; ks < 2; ks++) {
      short8 av[4], bv[4];
#pragma unroll
      for (int m = 0; m < 4; m++) av[m] = *(const short8*)&As[wr + m*16 + lr][ks*32 + lg*8];
#pragma unroll
      for (int n = 0; n < 4; n++) bv[n] = *(const short8*)&Bs[wc + n*16 + lr][ks*32 + lg*8];
#pragma unroll
      for (int m = 0; m < 4; m++)
#pragma unroll
        for (int n = 0; n < 4; n++)
          acc[m][n] = MFMA(av[m], bv[n], acc[m][n]);
    }
    __syncthreads();
  }
  u16* Ob = Out + (size_t)b * kCHW;
#pragma unroll
  for (int m = 0; m < 4; m++)
#pragma unroll
    for (int r = 0; r < 4; r++) {
      int o = bm + wr + m*16 + lg*4 + r;
      float bv_ = bias[o];
#pragma unroll
      for (int n = 0; n < 4; n++)
        Ob[(size_t)o * kHW + bn + wc + n*16 + lr] = f2b(acc[m][n][r] + bv_);
    }
}

// ---------- Gram: G[b][i][j] = sum_n F[b][i][n]*F[b][j][n] (A.A^T), 64x64 tile ----------
__global__ __launch_bounds__(256) void k_gram(const u16* __restrict__ F,
                                              float* __restrict__ G) {
  int b = blockIdx.z;
  int bm = blockIdx.y * 64, bn = blockIdx.x * 64;
  const u16* Fb = F + (size_t)b * kCHW;
  __shared__ u16 As[64][72];
  __shared__ u16 Bs[64][72];
  int tid = threadIdx.x;
  int lane = tid & 63, wv = tid >> 6;
  int wr = (wv >> 1) * 32, wc = (wv & 1) * 32;
  int lr = lane & 15, lg = lane >> 4;
  f32x4 acc[2][2] = {};
  for (int k0 = 0; k0 < kHW; k0 += 64) {
#pragma unroll
    for (int p = 0; p < 2; p++) {
      int ch = tid + p * 256;
      int row = ch >> 3, seg = ch & 7;
      *(short8*)&As[row][seg*8] = *(const short8*)&Fb[(size_t)(bm+row)*kHW + k0 + seg*8];
      *(short8*)&Bs[row][seg*8] = *(const short8*)&Fb[(size_t)(bn+row)*kHW + k0 + seg*8];
    }
    __syncthreads();
#pragma unroll
    for (int ks = 0; ks < 2; ks++) {
      short8 av[2], bv[2];
#pragma unroll
      for (int m = 0; m < 2; m++) av[m] = *(const short8*)&As[wr + m*16 + lr][ks*32 + lg*8];
#pragma unroll
      for (int n = 0; n < 2; n++) bv[n] = *(const short8*)&Bs[wc + n*16 + lr][ks*32 + lg*8];
#pragma unroll
      for (int m = 0; m < 2; m++)
#pragma unroll
        for (int n = 0; n < 2; n++)
          acc[m][n] = MFMA(av[m], bv[n], acc[m][n]);
    }
    __syncthreads();
  }
  float* Gb = G + (size_t)b * 262144;
#pragma unroll
  for (int m = 0; m < 2; m++)
#pragma unroll
    for (int r = 0; r < 4; r++) {
      int i = bm + wr + m*16 + lg*4 + r;
#pragma unroll
      for (int n = 0; n < 2; n++)
        Gb[(size_t)i*512 + bn + wc + n*16 + lr] = acc[m][n][r];
    }
}

// ---------- row softmax over 512 (in-place) ----------
__global__ __launch_bounds__(256) void k_softmax512(float* __restrict__ G) {
  size_t row = blockIdx.x;
  float* R = G + row * 512;
  int tid = threadIdx.x;
  int wid = tid >> 6, lane = tid & 63;
  float v0 = R[tid], v1 = R[tid + 256];
  float m = fmaxf(v0, v1);
#pragma unroll
  for (int o = 32; o >= 1; o >>= 1) m = fmaxf(m, __shfl_xor(m, o));
  __shared__ float redm[4], reds[4];
  if (lane == 0) redm[wid] = m;
  __syncthreads();
  m = fmaxf(fmaxf(redm[0], redm[1]), fmaxf(redm[2], redm[3]));
  float e0 = expf(v0 - m), e1 = expf(v1 - m);
  float s = e0 + e1;
#pragma unroll
  for (int o = 32; o >= 1; o >>= 1) s += __shfl_xor(s, o);
  if (lane == 0) reds[wid] = s;
  __syncthreads();
  s = reds[0] + reds[1] + reds[2] + reds[3];
  float inv = 1.0f / s;
  R[tid] = e0 * inv;
  R[tid + 256] = e1 * inv;
}

// ---------- out_C: Out[b][hw][c] (flat == d_out) = gamma * f_chT . affT^T ----------
__global__ __launch_bounds__(256) void k_outc(
    const u16* __restrict__ AT, const u16* __restrict__ Bt,
    const float* __restrict__ gamma, float* __restrict__ Out) {
  int b = blockIdx.z;
  int bm = blockIdx.y * 128;   // hw
  int bn = blockIdx.x * 128;   // c
  const u16* Ab = AT + (size_t)b * kCHW;
  const u16* Bb = Bt + (size_t)b * 262144;
  __shared__ u16 As[128][72];
  __shared__ u16 Bs[128][72];
  int tid = threadIdx.x;
  int lane = tid & 63, wv = tid >> 6;
  int wr = (wv >> 1) * 64, wc = (wv & 1) * 64;
  int lr = lane & 15, lg = lane >> 4;
  f32x4 acc[4][4] = {};
  for (int k0 = 0; k0 < kC; k0 += 64) {
#pragma unroll
    for (int p = 0; p < 4; p++) {
      int ch = tid + p * 256;
      int row = ch >> 3, seg = ch & 7;
      *(short8*)&As[row][seg*8] = *(const short8*)&Ab[(size_t)(bm+row)*512 + k0 + seg*8];
      *(short8*)&Bs[row][seg*8] = *(const short8*)&Bb[(size_t)(bn+row)*512 + k0 + seg*8];
    }
    __syncthreads();
#pragma unroll
    for (int ks = 0; ks < 2; ks++) {
      short8 av[4], bv[4];
#pragma unroll
      for (int m = 0; m < 4; m++) av[m] = *(const short8*)&As[wr + m*16 + lr][ks*32 + lg*8];
#pragma unroll
      for (int n = 0; n < 4; n++) bv[n] = *(const short8*)&Bs[wc + n*16 + lr][ks*32 + lg*8];
#pragma unroll
      for (int m = 0; m < 4; m++)
#pragma unroll
        for (int n = 0; n < 4; n++)
          acc[m][n] = MFMA(av[m], bv[n], acc[m][n]);
    }
    __syncthreads();
  }
  float g = *gamma;
  float* Ob = Out + (size_t)b * kCHW;
#pragma unroll
  for (int m = 0; m < 4; m++)
#pragma unroll
    for (int r = 0; r < 4; r++) {
      int mm = bm + wr + m*16 + lg*4 + r;
#pragma unroll
      for (int n = 0; n < 4; n++)
        Ob[(size_t)mm * 512 + bn + wc + n*16 + lr] = g * acc[m][n][r];
    }
}

// ---------- E_h -> ccat[b,i,w, j<96] (bf16 out) ----------
__global__ __launch_bounds__(256) void k_eh(
    const float* __restrict__ fhei, const float* __restrict__ fwid,
    u16* __restrict__ Ccat) {
  int b = blockIdx.x / kW, w = blockIdx.x % kW;
  __shared__ float fh[kH][kCr];
  __shared__ float fw[kCr][kH];
  int tid = threadIdx.x;
  for (int l = tid; l < kH * kCr; l += 256) {
    int i = l >> 3, c = l & 7;
    fh[i][c] = fhei[((size_t)b * kCr + (i & 7)) * kHW + (c * 12 + (i >> 3)) * kW + w];
    int c2 = l / kH, j = l % kH;
    fw[c2][j] = fwid[((size_t)b * kCr + c2) * kHW + j * kW + w];
  }
  __syncthreads();
  for (int t = tid; t < kH * kH; t += 256) {
    int i = t / kH, j = t % kH;
    float e = 0.f;
#pragma unroll
    for (int c = 0; c < kCr; c++) e += fh[i][c] * fw[c][j];
    if (i == j) e += NEGV;
    Ccat[(((size_t)b * kH + i) * kW + w) * 192 + j] = f2b(e);
  }
}

// ---------- E_w -> ccat[b,h,w, 96+j] (bf16 out) ----------
__global__ __launch_bounds__(256) void k_ew(
    const float* __restrict__ fhei, const float* __restrict__ fwid,
    u16* __restrict__ Ccat) {
  int b = blockIdx.x / kH, h = blockIdx.x % kH;
  __shared__ float fh2[kCr][kW];
  __shared__ float fw2[kCr][kW];
  int tid = threadIdx.x;
  for (int l = tid; l < kCr * kW; l += 256) {
    int c = l / kW, w = l % kW;
    fh2[c][w] = fhei[((size_t)b * kCr + c) * kHW + h * kW + w];
    fw2[c][w] = fwid[((size_t)b * kCr + c) * kHW + h * kW + w];
  }
  __syncthreads();
  for (int t = tid; t < kW * kW; t += 256) {
    int w = t / kW, j = t % kW;
    float e = 0.f;
#pragma unroll
    for (int c = 0; c < kCr; c++) e += fh2[c][w] * fw2[c][j];
    Ccat[(((size_t)b * kH + h) * kW + w) * 192 + 96 + j] = f2b(e);
  }
}

// ---------- softmax over 192 (bf16 in-place), one wave per row ----------
__global__ __launch_bounds__(256) void k_softmax192(u16* __restrict__ Ccat) {
  int r = blockIdx.x * 4 + (threadIdx.x >> 6);
  int lane = threadIdx.x & 63;
  u16* R = Ccat + (size_t)r * 192;
  float a = b2f(R[lane]), b = b2f(R[lane + 64]), c = b2f(R[lane + 128]);
  float m = fmaxf(a, fmaxf(b, c));
#pragma unroll
  for (int o = 32; o >= 1; o >>= 1) m = fmaxf(m, __shfl_xor(m, o));
  float ea = expf(a - m), eb = expf(b - m), ec = expf(c - m);
  float s = ea + eb + ec;
#pragma unroll
  for (int o = 32; o >= 1; o >>= 1) s += __shfl_xor(s, o);
  float inv = 1.0f / s;
  R[lane] = f2b(ea * inv);
  R[lane + 64] = f2b(eb * inv);
  R[lane + 128] = f2b(ec * inv);
}

// ---------- per-(b,c) 96x96 plane transpose (bf16) ----------
__global__ __launch_bounds__(256) void k_tr_plane(const u16* __restrict__ in,
                                                  u16* __restrict__ out) {
  size_t pl = blockIdx.x;
  const u16* ib = in + pl * 9216;
  u16* ob = out + pl * 9216;
  __shared__ u16 T[96][100];
  int tid = threadIdx.x;
  for (int ch = tid; ch < 96 * 24; ch += 256) {
    int i = ch / 24, seg = ch % 24;
    *(us4*)&T[i][seg*4] = *(const us4*)&ib[i*96 + seg*4];
  }
  __syncthreads();
  for (int ch = tid; ch < 96 * 24; ch += 256) {
    int j = ch / 24, seg = ch % 24;
    us4 o;
#pragma unroll
    for (int e = 0; e < 4; e++) o[e] = T[seg*4+e][j];
    *(us4*)&ob[j*96 + seg*4] = o;
  }
}

// ---------- H-path: per (b,w): OutHT[b][c][w][h] = alpha * sum_j AT[c][j] att[h][j] ----------
__global__ __launch_bounds__(512) void k_final_h(
    const u16* __restrict__ AT,    // f_chaT [B][512][96(w)][96(j=h)]
    const u16* __restrict__ att,   // ccat bf16 [B][96][96][192]
    const float* __restrict__ alpha,
    u16* __restrict__ OutHT) {
  int b = blockIdx.x / 96, w = blockIdx.x % 96;
  __shared__ u16 Bs[96][104];
  int tid = threadIdx.x;
  for (int ch = tid; ch < 1152; ch += 512) {
    int h = ch / 12, seg = ch % 12;
    *(short8*)&Bs[h][seg*8] =
        *(const short8*)&att[(((size_t)b*96 + h)*96 + w)*192 + seg*8];
  }
  __syncthreads();
  int lane = tid & 63, wv = tid >> 6;
  int lr = lane & 15, lg = lane >> 4;
  int c0 = wv * 64;
  const u16* Ab = AT + ((size_t)b*512 + c0)*kHW + w*96;
  f32x4 acc[4][6] = {};
#pragma unroll
  for (int ks = 0; ks < 3; ks++) {
    short8 av[4];
#pragma unroll
    for (int m = 0; m < 4; m++)
      av[m] = *(const short8*)&Ab[(size_t)(m*16 + lr)*kHW + ks*32 + lg*8];
#pragma unroll
    for (int n = 0; n < 6; n++) {
      short8 bv = *(const short8*)&Bs[n*16 + lr][ks*32 + lg*8];
#pragma unroll
      for (int m = 0; m < 4; m++) acc[m][n] = MFMA(av[m], bv, acc[m][n]);
    }
  }
  float al = *alpha;
  u16* Ob = OutHT + ((size_t)b*512 + c0)*kHW + w*96;
#pragma unroll
  for (int m = 0; m < 4; m++)
#pragma unroll
    for (int r = 0; r < 4; r++) {
      size_t crow = (size_t)(m*16 + lg*4 + r) * kHW;
#pragma unroll
      for (int n = 0; n < 6; n++)
        Ob[crow + n*16 + lr] = f2b(al * acc[m][n][r]);
    }
}

// ---------- W-path + residual: out = x + out(gammaC) + beta*out_W ----------
__global__ __launch_bounds__(512) void k_final_w(
    const u16* __restrict__ A,     // f_cha [B][512][96(h)][96(j=w)]
    const u16* __restrict__ att,
    const float* __restrict__ x,
    const float* __restrict__ beta,
    float* __restrict__ out) {
  int b = blockIdx.x / 96, h = blockIdx.x % 96;
  __shared__ u16 Bs[96][104];
  int tid = threadIdx.x;
  for (int ch = tid; ch < 1152; ch += 512) {
    int wr_ = ch / 12, seg = ch % 12;
    *(short8*)&Bs[wr_][seg*8] =
        *(const short8*)&att[(((size_t)b*96 + h)*96 + wr_)*192 + 96 + seg*8];
  }
  __syncthreads();
  int lane = tid & 63, wv = tid >> 6;
  int lr = lane & 15, lg = lane >> 4;
  int c0 = wv * 64;
  const u16* Ab = A + ((size_t)b*512 + c0)*kHW + h*96;
  f32x4 acc[4][6] = {};
#pragma unroll
  for (int ks = 0; ks < 3; ks++) {
    short8 av[4];
#pragma unroll
    for (int m = 0; m < 4; m++)
      av[m] = *(const short8*)&Ab[(size_t)(m*16 + lr)*kHW + ks*32 + lg*8];
#pragma unroll
    for (int n = 0; n < 6; n++) {
      short8 bv = *(const short8*)&Bs[n*16 + lr][ks*32 + lg*8];
#pragma unroll
      for (int m = 0; m < 4; m++) acc[m][n] = MFMA(av[m], bv, acc[m][n]);
    }
  }
  float be = *beta;
  size_t base = ((size_t)b*512 + c0)*kHW + (size_t)h*96;
#pragma unroll
  for (int m = 0; m < 4; m++)
#pragma unroll
    for (int r = 0; r < 4; r++) {
      size_t o = base + (size_t)(m*16 + lg*4 + r)*kHW;
#pragma unroll
      for (int n = 0; n < 6; n++) {
        size_t oo = o + n*16 + lr;
        out[oo] = x[oo] + out[oo] + be * acc[m][n][r];
      }
    }
}

// ---------- add H-path back with plane transpose: out[.,h,w] += HT[.,w,h] ----------
__global__ __launch_bounds__(256) void k_add_h(const u16* __restrict__ HT,
                                               float* __restrict__ out) {
  size_t pl = blockIdx.x;
  const u16* ib = HT + pl * 9216;
  float* ob = out + pl * 9216;
  __shared__ u16 T[96][100];
  int tid = threadIdx.x;
  for (int ch = tid; ch < 96 * 24; ch += 256) {
    int i = ch / 24, seg = ch % 24;
    *(us4*)&T[i][seg*4] = *(const us4*)&ib[i*96 + seg*4];
  }
  __syncthreads();
  for (int i = tid; i < 9216; i += 256) {
    int h = i / 96, w = i % 96;
    ob[i] += b2f(T[w][h]);
  }
}

extern "C" void kernel_launch(void* const* d_in, const int* in_sizes, int n_in,
                              void* d_out, int out_size, void* d_ws, size_t ws_size,
                              hipStream_t stream) {
  const float* x     = (const float*)d_in[0];
  const float* w_h   = (const float*)d_in[1];
  const float* b_h   = (const float*)d_in[2];
  const float* w_w   = (const float*)d_in[3];
  const float* b_w   = (const float*)d_in[4];
  const float* w_c   = (const float*)d_in[5];
  const float* b_c   = (const float*)d_in[6];
  const float* w_o   = (const float*)d_in[7];
  const float* b_o   = (const float*)d_in[8];
  const float* alpha = (const float*)d_in[9];
  const float* beta  = (const float*)d_in[10];
  const float* gamma = (const float*)d_in[11];
  float* out = (float*)d_out;

  char* p = (char*)d_ws;
  u16* xbfT  = (u16*)p;  p += 37748736;   // [B][9216][512]; later reused as f_chaT
  u16* f_ch  = (u16*)p;  p += 37748736;   // [B][512][9216]
  u16* f_chT = (u16*)p;  p += 37748736;   // [B][9216][512]; later reused as outHT
  u16* f_cha = (u16*)p;  p += 37748736;   // [B][512][9216]
  float* f_hei = (float*)p; p += 4718592;
  float* f_wid = (float*)p; p += 4718592;
  char* scratch = p;                       // 14155776 B scratch region
  u16* wcbf   = (u16*)scratch;
  u16* wobf   = (u16*)(scratch + 524288);
  float* gramP = (float*)(scratch + 1048576);            // 4.19 MB
  u16* affT   = (u16*)(scratch + 1048576 + 4194304);     // 2.10 MB
  u16* ccat   = (u16*)scratch;             // aliases wcbf/wobf/gramP/affT (used after k_outc)
  u16* f_chaT = xbfT;
  u16* outHT  = f_chT;

  k_cvt_T<<<dim3(144, 8, 4), 256, 0, stream>>>(x, xbfT, 512, 9216);
  k_cvt<<<256, 256, 0, stream>>>(w_c, wcbf, 65536);
  k_cvt<<<256, 256, 0, stream>>>(w_o, wobf, 65536);
  k_conv_small<<<144, 256, 0, stream>>>(x, w_h, b_h, w_w, b_w, f_hei, f_wid);
  k_gemm_conv<<<dim3(72, 4, 4), 256, 0, stream>>>(wcbf, xbfT, b_c, f_ch);
  k_gemm_conv<<<dim3(72, 4, 4), 256, 0, stream>>>(wobf, xbfT, b_o, f_cha);
  k_trT_bf<<<dim3(144, 8, 4), 256, 0, stream>>>(f_ch, f_chT, 512, 9216);
  k_gram<<<dim3(8, 8, 4), 256, 0, stream>>>(f_ch, gramP);
  k_softmax512<<<2048, 256, 0, stream>>>(gramP);
  k_cvt_T<<<dim3(8, 8, 4), 256, 0, stream>>>(gramP, affT, 512, 512);
  k_outc<<<dim3(4, 72, 4), 256, 0, stream>>>(f_chT, affT, gamma, out);
  k_eh<<<384, 256, 0, stream>>>(f_hei, f_wid, ccat);
  k_ew<<<384, 256, 0, stream>>>(f_hei, f_wid, ccat);
  k_softmax192<<<9216, 256, 0, stream>>>(ccat);
  k_tr_plane<<<2048, 256, 0, stream>>>(f_cha, f_chaT);
  k_final_h<<<384, 512, 0, stream>>>(f_chaT, ccat, alpha, outHT);
  k_final_w<<<384, 512, 0, stream>>>(f_cha, ccat, x, beta, out);
  k_add_h<<<2048, 256, 0, stream>>>(outHT, out);
}

// Round 3
// 418.938 us; speedup vs baseline: 6.5850x; 1.2268x over previous
//
#include <hip/hip_runtime.h>

typedef __attribute__((ext_vector_type(8))) short short8;
typedef __attribute__((ext_vector_type(4))) float f32x4;
typedef __attribute__((ext_vector_type(4))) unsigned short us4;
typedef unsigned short u16;

#define kB 4
#define kC 512
#define kCr 8
#define kH 96
#define kW 96
#define kHW 9216
#define kCHW 4718592
#define NEGV -1e9f

__device__ __forceinline__ u16 f2b(float f) {
  union { float f; unsigned u; } v; v.f = f;
  unsigned r = v.u + 0x7fff + ((v.u >> 16) & 1);
  return (u16)(r >> 16);
}
__device__ __forceinline__ float b2f(u16 h) {
  union { unsigned u; float f; } v; v.u = ((unsigned)h) << 16;
  return v.f;
}
#define MFMA(a, b, c) __builtin_amdgcn_mfma_f32_16x16x32_bf16(a, b, c, 0, 0, 0)

// ---------- fp32 [R][C] -> bf16 [C][R] transpose-convert, 64x64 tiles ----------
__global__ __launch_bounds__(256) void k_cvt_T(const float* __restrict__ in,
                                               u16* __restrict__ out,
                                               int R, int C) {
  const float* ib = in + (size_t)blockIdx.z * R * C;
  u16* ob = out + (size_t)blockIdx.z * R * C;
  int c0 = blockIdx.x * 64, r0 = blockIdx.y * 64;
  __shared__ u16 T[64][68];
  int tid = threadIdx.x;
#pragma unroll
  for (int p = 0; p < 4; p++) {
    int ch = tid + p * 256;
    int i = ch >> 4, seg = ch & 15;
    f32x4 v = *(const f32x4*)&ib[(size_t)(r0 + i) * C + c0 + seg * 4];
    T[i][seg*4+0] = f2b(v[0]); T[i][seg*4+1] = f2b(v[1]);
    T[i][seg*4+2] = f2b(v[2]); T[i][seg*4+3] = f2b(v[3]);
  }
  __syncthreads();
#pragma unroll
  for (int p = 0; p < 4; p++) {
    int ch = tid + p * 256;
    int j = ch >> 4, seg = ch & 15;
    us4 o;
#pragma unroll
    for (int e = 0; e < 4; e++) o[e] = T[seg*4+e][j];
    *(us4*)&ob[(size_t)(c0 + j) * R + r0 + seg * 4] = o;
  }
}

// ---------- bf16 [R][C] -> bf16 [C][R] transpose, 64x64 tiles ----------
__global__ __launch_bounds__(256) void k_trT_bf(const u16* __restrict__ in,
                                                u16* __restrict__ out,
                                                int R, int C) {
  const u16* ib = in + (size_t)blockIdx.z * R * C;
  u16* ob = out + (size_t)blockIdx.z * R * C;
  int c0 = blockIdx.x * 64, r0 = blockIdx.y * 64;
  __shared__ u16 T[64][68];
  int tid = threadIdx.x;
#pragma unroll
  for (int p = 0; p < 4; p++) {
    int ch = tid + p * 256;
    int i = ch >> 4, seg = ch & 15;
    us4 v = *(const us4*)&ib[(size_t)(r0 + i) * C + c0 + seg * 4];
    T[i][seg*4+0] = v[0]; T[i][seg*4+1] = v[1];
    T[i][seg*4+2] = v[2]; T[i][seg*4+3] = v[3];
  }
  __syncthreads();
#pragma unroll
  for (int p = 0; p < 4; p++) {
    int ch = tid + p * 256;
    int j = ch >> 4, seg = ch & 15;
    us4 o;
#pragma unroll
    for (int e = 0; e < 4; e++) o[e] = T[seg*4+e][j];
    *(us4*)&ob[(size_t)(c0 + j) * R + r0 + seg * 4] = o;
  }
}

// ---------- small convs: f_hei, f_wid [B,8,H,W] (fp32, cheap) ----------
__global__ __launch_bounds__(256) void k_conv_small(
    const float* __restrict__ x,
    const float* __restrict__ w_h, const float* __restrict__ b_h,
    const float* __restrict__ w_w, const float* __restrict__ b_w,
    float* __restrict__ f_hei, float* __restrict__ f_wid) {
  __shared__ float wh_s[kCr * kC];
  __shared__ float ww_s[kCr * kC];
  int tid = threadIdx.x;
  for (int l = tid; l < kCr * kC; l += 256) {
    wh_s[l] = w_h[l];
    ww_s[l] = w_w[l];
  }
  __syncthreads();
  int g = blockIdx.x * 256 + tid;
  int b = g / kHW, hw = g % kHW;
  float accH[kCr] = {0.f}, accW[kCr] = {0.f};
  const float* xb = x + (size_t)b * kCHW + hw;
  for (int c = 0; c < kC; c++) {
    float xv = xb[(size_t)c * kHW];
#pragma unroll
    for (int r = 0; r < kCr; r++) {
      accH[r] += wh_s[r * kC + c] * xv;
      accW[r] += ww_s[r * kC + c] * xv;
    }
  }
#pragma unroll
  for (int r = 0; r < kCr; r++) {
    f_hei[((size_t)b * kCr + r) * kHW + hw] = accH[r] + b_h[r];
    f_wid[((size_t)b * kCr + r) * kHW + hw] = accW[r] + b_w[r];
  }
}

// ---------- conv1x1 MFMA GEMM: Out[b][o][n] = sum_c W[o][c]*XT[b][n][c] + bias ----------
// A = W fp32 [512][512] (converted during staging), B = xbfT [B][9216][512]; A.B^T.
__global__ __launch_bounds__(256) void k_gemm_conv(
    const float* __restrict__ A, const u16* __restrict__ BT,
    const float* __restrict__ bias, u16* __restrict__ Out) {
  int b = blockIdx.z;
  int bm = blockIdx.y * 128;   // o
  int bn = blockIdx.x * 128;   // hw
  const u16* Bb = BT + (size_t)b * kCHW;
  __shared__ u16 As[128][72];
  __shared__ u16 Bs[128][72];
  int tid = threadIdx.x;
  int lane = tid & 63, wv = tid >> 6;
  int wr = (wv >> 1) * 64, wc = (wv & 1) * 64;
  int lr = lane & 15, lg = lane >> 4;
  f32x4 acc[4][4] = {};
  for (int k0 = 0; k0 < kC; k0 += 64) {
#pragma unroll
    for (int p = 0; p < 4; p++) {
      int ch = tid + p * 256;
      int row = ch >> 3, seg = ch & 7;
      const float* src = &A[(size_t)(bm + row) * 512 + k0 + seg * 8];
      f32x4 v0 = *(const f32x4*)src;
      f32x4 v1 = *(const f32x4*)(src + 4);
      short8 sv;
      sv[0]=f2b(v0[0]); sv[1]=f2b(v0[1]); sv[2]=f2b(v0[2]); sv[3]=f2b(v0[3]);
      sv[4]=f2b(v1[0]); sv[5]=f2b(v1[1]); sv[6]=f2b(v1[2]); sv[7]=f2b(v1[3]);
      *(short8*)&As[row][seg*8] = sv;
      *(short8*)&Bs[row][seg*8] = *(const short8*)&Bb[(size_t)(bn+row)*512 + k0 + seg*8];
    }
    __syncthreads();
#pragma unroll
    for (int ks = 0; ks < 2; ks++) {
      short8 av[4], bv[4];
#pragma unroll
      for (int m = 0; m < 4; m++) av[m] = *(const short8*)&As[wr + m*16 + lr][ks*32 + lg*8];
#pragma unroll
      for (int n = 0; n < 4; n++) bv[n] = *(const short8*)&Bs[wc + n*16 + lr][ks*32 + lg*8];
#pragma unroll
      for (int m = 0; m < 4; m++)
#pragma unroll
        for (int n = 0; n < 4; n++)
          acc[m][n] = MFMA(av[m], bv[n], acc[m][n]);
    }
    __syncthreads();
  }
  u16* Ob = Out + (size_t)b * kCHW;
#pragma unroll
  for (int m = 0; m < 4; m++)
#pragma unroll
    for (int r = 0; r < 4; r++) {
      int o = bm + wr + m*16 + lg*4 + r;
      float bv_ = bias[o];
#pragma unroll
      for (int n = 0; n < 4; n++)
        Ob[(size_t)o * kHW + bn + wc + n*16 + lr] = f2b(acc[m][n][r] + bv_);
    }
}

// ---------- Gram split-K: part[s][b][i][j] = sum_{n in chunk s} F[b][i][n]F[b][j][n] ----------
// 128x128 tile, BK=64, K-chunk = 9216/8 = 1152 (18 iters). grid (4,4,32): z = s*4+b... (b=z&3,s=z>>2)
__global__ __launch_bounds__(256) void k_gram_sk(const u16* __restrict__ F,
                                                float* __restrict__ part) {
  int z = blockIdx.z;
  int b = z & 3, s = z >> 2;
  int bm = blockIdx.y * 128, bn = blockIdx.x * 128;
  const u16* Fb = F + (size_t)b * kCHW;
  __shared__ u16 As[128][72];
  __shared__ u16 Bs[128][72];
  int tid = threadIdx.x;
  int lane = tid & 63, wv = tid >> 6;
  int wr = (wv >> 1) * 64, wc = (wv & 1) * 64;
  int lr = lane & 15, lg = lane >> 4;
  f32x4 acc[4][4] = {};
  int kbeg = s * 1152;
  for (int k0 = kbeg; k0 < kbeg + 1152; k0 += 64) {
#pragma unroll
    for (int p = 0; p < 4; p++) {
      int ch = tid + p * 256;
      int row = ch >> 3, seg = ch & 7;
      *(short8*)&As[row][seg*8] = *(const short8*)&Fb[(size_t)(bm+row)*kHW + k0 + seg*8];
      *(short8*)&Bs[row][seg*8] = *(const short8*)&Fb[(size_t)(bn+row)*kHW + k0 + seg*8];
    }
    __syncthreads();
#pragma unroll
    for (int ks = 0; ks < 2; ks++) {
      short8 av[4], bv[4];
#pragma unroll
      for (int m = 0; m < 4; m++) av[m] = *(const short8*)&As[wr + m*16 + lr][ks*32 + lg*8];
#pragma unroll
      for (int n = 0; n < 4; n++) bv[n] = *(const short8*)&Bs[wc + n*16 + lr][ks*32 + lg*8];
#pragma unroll
      for (int m = 0; m < 4; m++)
#pragma unroll
        for (int n = 0; n < 4; n++)
          acc[m][n] = MFMA(av[m], bv[n], acc[m][n]);
    }
    __syncthreads();
  }
  float* Pb = part + ((size_t)(s * 4 + b)) * 262144;
#pragma unroll
  for (int m = 0; m < 4; m++)
#pragma unroll
    for (int r = 0; r < 4; r++) {
      int i = bm + wr + m*16 + lg*4 + r;
#pragma unroll
      for (int n = 0; n < 4; n++)
        Pb[(size_t)i * 512 + bn + wc + n*16 + lr] = acc[m][n][r];
    }
}

// ---------- 8-way partial reduce + row softmax over 512 -> gramN fp32 ----------
__global__ __launch_bounds__(256) void k_softmax512r(const float* __restrict__ part,
                                                     float* __restrict__ gramN) {
  int b = blockIdx.x >> 9, i = blockIdx.x & 511;
  int tid = threadIdx.x;
  float v0 = 0.f, v1 = 0.f;
#pragma unroll
  for (int s = 0; s < 8; s++) {
    const float* P = part + ((size_t)(s * 4 + b) * 512 + i) * 512;
    v0 += P[tid];
    v1 += P[tid + 256];
  }
  int wid = tid >> 6, lane = tid & 63;
  float m = fmaxf(v0, v1);
#pragma unroll
  for (int o = 32; o >= 1; o >>= 1) m = fmaxf(m, __shfl_xor(m, o));
  __shared__ float redm[4], reds[4];
  if (lane == 0) redm[wid] = m;
  __syncthreads();
  m = fmaxf(fmaxf(redm[0], redm[1]), fmaxf(redm[2], redm[3]));
  float e0 = expf(v0 - m), e1 = expf(v1 - m);
  float s = e0 + e1;
#pragma unroll
  for (int o = 32; o >= 1; o >>= 1) s += __shfl_xor(s, o);
  if (lane == 0) reds[wid] = s;
  __syncthreads();
  s = reds[0] + reds[1] + reds[2] + reds[3];
  float inv = 1.0f / s;
  float* R = gramN + ((size_t)b * 512 + i) * 512;
  R[tid] = e0 * inv;
  R[tid + 256] = e1 * inv;
}

// ---------- out_C GEMM -> bf16 OutC[b][hw][c] (flat == d_out order) ----------
__global__ __launch_bounds__(256) void k_outc(
    const u16* __restrict__ AT, const u16* __restrict__ Bt,
    const float* __restrict__ gamma, u16* __restrict__ Out) {
  int b = blockIdx.z;
  int bm = blockIdx.y * 128;   // hw
  int bn = blockIdx.x * 128;   // c
  const u16* Ab = AT + (size_t)b * kCHW;
  const u16* Bb = Bt + (size_t)b * 262144;
  __shared__ u16 As[128][72];
  __shared__ u16 Bs[128][72];
  int tid = threadIdx.x;
  int lane = tid & 63, wv = tid >> 6;
  int wr = (wv >> 1) * 64, wc = (wv & 1) * 64;
  int lr = lane & 15, lg = lane >> 4;
  f32x4 acc[4][4] = {};
  for (int k0 = 0; k0 < kC; k0 += 64) {
#pragma unroll
    for (int p = 0; p < 4; p++) {
      int ch = tid + p * 256;
      int row = ch >> 3, seg = ch & 7;
      *(short8*)&As[row][seg*8] = *(const short8*)&Ab[(size_t)(bm+row)*512 + k0 + seg*8];
      *(short8*)&Bs[row][seg*8] = *(const short8*)&Bb[(size_t)(bn+row)*512 + k0 + seg*8];
    }
    __syncthreads();
#pragma unroll
    for (int ks = 0; ks < 2; ks++) {
      short8 av[4], bv[4];
#pragma unroll
      for (int m = 0; m < 4; m++) av[m] = *(const short8*)&As[wr + m*16 + lr][ks*32 + lg*8];
#pragma unroll
      for (int n = 0; n < 4; n++) bv[n] = *(const short8*)&Bs[wc + n*16 + lr][ks*32 + lg*8];
#pragma unroll
      for (int m = 0; m < 4; m++)
#pragma unroll
        for (int n = 0; n < 4; n++)
          acc[m][n] = MFMA(av[m], bv[n], acc[m][n]);
    }
    __syncthreads();
  }
  float g = *gamma;
  u16* Ob = Out + (size_t)b * kCHW;
#pragma unroll
  for (int m = 0; m < 4; m++)
#pragma unroll
    for (int r = 0; r < 4; r++) {
      int mm = bm + wr + m*16 + lg*4 + r;
#pragma unroll
      for (int n = 0; n < 4; n++)
        Ob[(size_t)mm * 512 + bn + wc + n*16 + lr] = f2b(g * acc[m][n][r]);
    }
}

// ---------- E_h -> ccat[b,i,w, j<96] (bf16 out) ----------
__global__ __launch_bounds__(256) void k_eh(
    const float* __restrict__ fhei, const float* __restrict__ fwid,
    u16* __restrict__ Ccat) {
  int b = blockIdx.x / kW, w = blockIdx.x % kW;
  __shared__ float fh[kH][kCr];
  __shared__ float fw[kCr][kH];
  int tid = threadIdx.x;
  for (int l = tid; l < kH * kCr; l += 256) {
    int i = l >> 3, c = l & 7;
    fh[i][c] = fhei[((size_t)b * kCr + (i & 7)) * kHW + (c * 12 + (i >> 3)) * kW + w];
    int c2 = l / kH, j = l % kH;
    fw[c2][j] = fwid[((size_t)b * kCr + c2) * kHW + j * kW + w];
  }
  __syncthreads();
  for (int t = tid; t < kH * kH; t += 256) {
    int i = t / kH, j = t % kH;
    float e = 0.f;
#pragma unroll
    for (int c = 0; c < kCr; c++) e += fh[i][c] * fw[c][j];
    if (i == j) e += NEGV;
    Ccat[(((size_t)b * kH + i) * kW + w) * 192 + j] = f2b(e);
  }
}

// ---------- E_w -> ccat[b,h,w, 96+j] (bf16 out) ----------
__global__ __launch_bounds__(256) void k_ew(
    const float* __restrict__ fhei, const float* __restrict__ fwid,
    u16* __restrict__ Ccat) {
  int b = blockIdx.x / kH, h = blockIdx.x % kH;
  __shared__ float fh2[kCr][kW];
  __shared__ float fw2[kCr][kW];
  int tid = threadIdx.x;
  for (int l = tid; l < kCr * kW; l += 256) {
    int c = l / kW, w = l % kW;
    fh2[c][w] = fhei[((size_t)b * kCr + c) * kHW + h * kW + w];
    fw2[c][w] = fwid[((size_t)b * kCr + c) * kHW + h * kW + w];
  }
  __syncthreads();
  for (int t = tid; t < kW * kW; t += 256) {
    int w = t / kW, j = t % kW;
    float e = 0.f;
#pragma unroll
    for (int c = 0; c < kCr; c++) e += fh2[c][w] * fw2[c][j];
    Ccat[(((size_t)b * kH + h) * kW + w) * 192 + 96 + j] = f2b(e);
  }
}

// ---------- softmax over 192 (bf16 in-place), one wave per row ----------
__global__ __launch_bounds__(256) void k_softmax192(u16* __restrict__ Ccat) {
  int r = blockIdx.x * 4 + (threadIdx.x >> 6);
  int lane = threadIdx.x & 63;
  u16* R = Ccat + (size_t)r * 192;
  float a = b2f(R[lane]), b = b2f(R[lane + 64]), c = b2f(R[lane + 128]);
  float m = fmaxf(a, fmaxf(b, c));
#pragma unroll
  for (int o = 32; o >= 1; o >>= 1) m = fmaxf(m, __shfl_xor(m, o));
  float ea = expf(a - m), eb = expf(b - m), ec = expf(c - m);
  float s = ea + eb + ec;
#pragma unroll
  for (int o = 32; o >= 1; o >>= 1) s += __shfl_xor(s, o);
  float inv = 1.0f / s;
  R[lane] = f2b(ea * inv);
  R[lane + 64] = f2b(eb * inv);
  R[lane + 128] = f2b(ec * inv);
}

// ---------- per-(b,c) 96x96 plane transpose (bf16) ----------
__global__ __launch_bounds__(256) void k_tr_plane(const u16* __restrict__ in,
                                                  u16* __restrict__ out) {
  size_t pl = blockIdx.x;
  const u16* ib = in + pl * 9216;
  u16* ob = out + pl * 9216;
  __shared__ u16 T[96][100];
  int tid = threadIdx.x;
  for (int ch = tid; ch < 96 * 24; ch += 256) {
    int i = ch / 24, seg = ch % 24;
    *(us4*)&T[i][seg*4] = *(const us4*)&ib[i*96 + seg*4];
  }
  __syncthreads();
  for (int ch = tid; ch < 96 * 24; ch += 256) {
    int j = ch / 24, seg = ch % 24;
    us4 o;
#pragma unroll
    for (int e = 0; e < 4; e++) o[e] = T[seg*4+e][j];
    *(us4*)&ob[j*96 + seg*4] = o;
  }
}

// ---------- H-path: per (b,w): HT[b][c][w][h] = alpha * sum_j AT[c][j] att[h][j] ----------
__global__ __launch_bounds__(512) void k_final_h(
    const u16* __restrict__ AT,    // f_chaT [B][512][96(w)][96(j=h)]
    const u16* __restrict__ att,   // ccat bf16 [B][96][96][192]
    const float* __restrict__ alpha,
    u16* __restrict__ OutHT) {
  int b = blockIdx.x / 96, w = blockIdx.x % 96;
  __shared__ u16 Bs[96][104];
  int tid = threadIdx.x;
  for (int ch = tid; ch < 1152; ch += 512) {
    int h = ch / 12, seg = ch % 12;
    *(short8*)&Bs[h][seg*8] =
        *(const short8*)&att[(((size_t)b*96 + h)*96 + w)*192 + seg*8];
  }
  __syncthreads();
  int lane = tid & 63, wv = tid >> 6;
  int lr = lane & 15, lg = lane >> 4;
  int c0 = wv * 64;
  const u16* Ab = AT + ((size_t)b*512 + c0)*kHW + w*96;
  f32x4 acc[4][6] = {};
#pragma unroll
  for (int ks = 0; ks < 3; ks++) {
    short8 av[4];
#pragma unroll
    for (int m = 0; m < 4; m++)
      av[m] = *(const short8*)&Ab[(size_t)(m*16 + lr)*kHW + ks*32 + lg*8];
#pragma unroll
    for (int n = 0; n < 6; n++) {
      short8 bv = *(const short8*)&Bs[n*16 + lr][ks*32 + lg*8];
#pragma unroll
      for (int m = 0; m < 4; m++) acc[m][n] = MFMA(av[m], bv, acc[m][n]);
    }
  }
  float al = *alpha;
  u16* Ob = OutHT + ((size_t)b*512 + c0)*kHW + w*96;
#pragma unroll
  for (int m = 0; m < 4; m++)
#pragma unroll
    for (int r = 0; r < 4; r++) {
      size_t crow = (size_t)(m*16 + lg*4 + r) * kHW;
#pragma unroll
      for (int n = 0; n < 6; n++)
        Ob[crow + n*16 + lr] = f2b(al * acc[m][n][r]);
    }
}

// ---------- W-path: per (b,h): OutW[b][c][h][w] = beta * sum_j A[c][j] att[w][96+j] ----------
__global__ __launch_bounds__(512) void k_final_w(
    const u16* __restrict__ A,     // f_cha [B][512][96(h)][96(j=w)]
    const u16* __restrict__ att,
    const float* __restrict__ beta,
    u16* __restrict__ OutW) {
  int b = blockIdx.x / 96, h = blockIdx.x % 96;
  __shared__ u16 Bs[96][104];
  int tid = threadIdx.x;
  for (int ch = tid; ch < 1152; ch += 512) {
    int wr_ = ch / 12, seg = ch % 12;
    *(short8*)&Bs[wr_][seg*8] =
        *(const short8*)&att[(((size_t)b*96 + h)*96 + wr_)*192 + 96 + seg*8];
  }
  __syncthreads();
  int lane = tid & 63, wv = tid >> 6;
  int lr = lane & 15, lg = lane >> 4;
  int c0 = wv * 64;
  const u16* Ab = A + ((size_t)b*512 + c0)*kHW + h*96;
  f32x4 acc[4][6] = {};
#pragma unroll
  for (int ks = 0; ks < 3; ks++) {
    short8 av[4];
#pragma unroll
    for (int m = 0; m < 4; m++)
      av[m] = *(const short8*)&Ab[(size_t)(m*16 + lr)*kHW + ks*32 + lg*8];
#pragma unroll
    for (int n = 0; n < 6; n++) {
      short8 bv = *(const short8*)&Bs[n*16 + lr][ks*32 + lg*8];
#pragma unroll
      for (int m = 0; m < 4; m++) acc[m][n] = MFMA(av[m], bv, acc[m][n]);
    }
  }
  float be = *beta;
  u16* Ob = OutW + ((size_t)b*512 + c0)*kHW + h*96;
#pragma unroll
  for (int m = 0; m < 4; m++)
#pragma unroll
    for (int r = 0; r < 4; r++) {
      size_t crow = (size_t)(m*16 + lg*4 + r) * kHW;
#pragma unroll
      for (int n = 0; n < 6; n++)
        Ob[crow + n*16 + lr] = f2b(be * acc[m][n][r]);
    }
}

// ---------- merge: out = x + OutC + OutW + HT^T(per plane) ----------
__global__ __launch_bounds__(256) void k_merge(
    const float* __restrict__ x, const u16* __restrict__ OutC,
    const u16* __restrict__ OutW, const u16* __restrict__ HT,
    float* __restrict__ out) {
  size_t pl = blockIdx.x;
  const u16* hb = HT + pl * 9216;
  __shared__ u16 T[96][100];
  int tid = threadIdx.x;
  for (int ch = tid; ch < 96 * 24; ch += 256) {
    int i = ch / 24, seg = ch % 24;
    *(us4*)&T[i][seg*4] = *(const us4*)&hb[i*96 + seg*4];
  }
  __syncthreads();
  const float* xb = x + pl * 9216;
  const u16* cb = OutC + pl * 9216;
  const u16* wb = OutW + pl * 9216;
  float* ob = out + pl * 9216;
  for (int ch = tid; ch < 2304; ch += 256) {
    int i4 = ch * 4;
    int h = i4 / 96, w = i4 % 96;
    f32x4 xv = *(const f32x4*)&xb[i4];
    us4 cv = *(const us4*)&cb[i4];
    us4 wv = *(const us4*)&wb[i4];
    f32x4 o;
#pragma unroll
    for (int e = 0; e < 4; e++)
      o[e] = xv[e] + b2f(cv[e]) + b2f(wv[e]) + b2f(T[w + e][h]);
    *(f32x4*)&ob[i4] = o;
  }
}

extern "C" void kernel_launch(void* const* d_in, const int* in_sizes, int n_in,
                              void* d_out, int out_size, void* d_ws, size_t ws_size,
                              hipStream_t stream) {
  const float* x     = (const float*)d_in[0];
  const float* w_h   = (const float*)d_in[1];
  const float* b_h   = (const float*)d_in[2];
  const float* w_w   = (const float*)d_in[3];
  const float* b_w   = (const float*)d_in[4];
  const float* w_c   = (const float*)d_in[5];
  const float* b_c   = (const float*)d_in[6];
  const float* w_o   = (const float*)d_in[7];
  const float* b_o   = (const float*)d_in[8];
  const float* alpha = (const float*)d_in[9];
  const float* beta  = (const float*)d_in[10];
  const float* gamma = (const float*)d_in[11];
  float* out = (float*)d_out;

  // Region plan (bytes). R = 37748736 (one [B][512][9216] bf16 buffer).
  //  A [0,R):        xbfT (steps1-4) / gram partials 33.5MB (6-7) / f_chaT (13-14) / OutW (15-16)
  //  B [R,2R):       f_ch (3-6) / OutC (9-16)
  //  C [2R,3R):      f_chT (5-9) / HT (14-16)
  //  D [3R,4R):      f_cha (4-15)
  //  E: f_hei,f_wid fp32 (2-11)
  //  F: gramN(4.19M,7-8)+affT(2.10M,8-9) overlaid by ccat 14.16M (10-15)
  const size_t R = 37748736;
  char* p = (char*)d_ws;
  u16*   xbfT   = (u16*)(p);
  float* part   = (float*)(p);
  u16*   f_chaT = (u16*)(p);
  u16*   outW   = (u16*)(p);
  u16*   f_ch   = (u16*)(p + R);
  u16*   outC   = (u16*)(p + R);
  u16*   f_chT  = (u16*)(p + 2 * R);
  u16*   outHT  = (u16*)(p + 2 * R);
  u16*   f_cha  = (u16*)(p + 3 * R);
  float* f_hei  = (float*)(p + 4 * R);
  float* f_wid  = (float*)(p + 4 * R + 1179648);
  char*  F      = p + 4 * R + 2359296;
  float* gramN  = (float*)F;
  u16*   affT   = (u16*)(F + 4194304);
  u16*   ccat   = (u16*)F;

  k_cvt_T<<<dim3(144, 8, 4), 256, 0, stream>>>(x, xbfT, 512, 9216);
  k_conv_small<<<144, 256, 0, stream>>>(x, w_h, b_h, w_w, b_w, f_hei, f_wid);
  k_gemm_conv<<<dim3(72, 4, 4), 256, 0, stream>>>(w_c, xbfT, b_c, f_ch);
  k_gemm_conv<<<dim3(72, 4, 4), 256, 0, stream>>>(w_o, xbfT, b_o, f_cha);
  k_trT_bf<<<dim3(144, 8, 4), 256, 0, stream>>>(f_ch, f_chT, 512, 9216);
  k_gram_sk<<<dim3(4, 4, 32), 256, 0, stream>>>(f_ch, part);
  k_softmax512r<<<2048, 256, 0, stream>>>(part, gramN);
  k_cvt_T<<<dim3(8, 8, 4), 256, 0, stream>>>(gramN, affT, 512, 512);
  k_outc<<<dim3(4, 72, 4), 256, 0, stream>>>(f_chT, affT, gamma, outC);
  k_eh<<<384, 256, 0, stream>>>(f_hei, f_wid, ccat);
  k_ew<<<384, 256, 0, stream>>>(f_hei, f_wid, ccat);
  k_softmax192<<<9216, 256, 0, stream>>>(ccat);
  k_tr_plane<<<2048, 256, 0, stream>>>(f_cha, f_chaT);
  k_final_h<<<384, 512, 0, stream>>>(f_chaT, ccat, alpha, outHT);
  k_final_w<<<384, 512, 0, stream>>>(f_cha, ccat, beta, outW);
  k_merge<<<2048, 256, 0, stream>>>(x, outC, outW, outHT, out);
}

// Round 4
// 342.117 us; speedup vs baseline: 8.0637x; 1.2245x over previous
//
#include <hip/hip_runtime.h>

typedef __attribute__((ext_vector_type(8))) short short8;
typedef __attribute__((ext_vector_type(4))) float f32x4;
typedef __attribute__((ext_vector_type(4))) unsigned short us4;
typedef unsigned short u16;

#define kB 4
#define kC 512
#define kCr 8
#define kH 96
#define kW 96
#define kHW 9216
#define kCHW 4718592
#define NEGV -1e9f

__device__ __forceinline__ u16 f2b(float f) {
  union { float f; unsigned u; } v; v.f = f;
  unsigned r = v.u + 0x7fff + ((v.u >> 16) & 1);
  return (u16)(r >> 16);
}
__device__ __forceinline__ float b2f(u16 h) {
  union { unsigned u; float f; } v; v.u = ((unsigned)h) << 16;
  return v.f;
}
#define MFMA(a, b, c) __builtin_amdgcn_mfma_f32_16x16x32_bf16(a, b, c, 0, 0, 0)

// ---------- fp32 [R][C] -> bf16 [C][R] transpose-convert, 64x64 tiles ----------
__global__ __launch_bounds__(256) void k_cvt_T(const float* __restrict__ in,
                                               u16* __restrict__ out,
                                               int R, int C) {
  const float* ib = in + (size_t)blockIdx.z * R * C;
  u16* ob = out + (size_t)blockIdx.z * R * C;
  int c0 = blockIdx.x * 64, r0 = blockIdx.y * 64;
  __shared__ u16 T[64][68];
  int tid = threadIdx.x;
#pragma unroll
  for (int p = 0; p < 4; p++) {
    int ch = tid + p * 256;
    int i = ch >> 4, seg = ch & 15;
    f32x4 v = *(const f32x4*)&ib[(size_t)(r0 + i) * C + c0 + seg * 4];
    T[i][seg*4+0] = f2b(v[0]); T[i][seg*4+1] = f2b(v[1]);
    T[i][seg*4+2] = f2b(v[2]); T[i][seg*4+3] = f2b(v[3]);
  }
  __syncthreads();
#pragma unroll
  for (int p = 0; p < 4; p++) {
    int ch = tid + p * 256;
    int j = ch >> 4, seg = ch & 15;
    us4 o;
#pragma unroll
    for (int e = 0; e < 4; e++) o[e] = T[seg*4+e][j];
    *(us4*)&ob[(size_t)(c0 + j) * R + r0 + seg * 4] = o;
  }
}

// ---------- bf16 [R][C] -> bf16 [C][R] transpose, 64x64 tiles ----------
__global__ __launch_bounds__(256) void k_trT_bf(const u16* __restrict__ in,
                                                u16* __restrict__ out,
                                                int R, int C) {
  const u16* ib = in + (size_t)blockIdx.z * R * C;
  u16* ob = out + (size_t)blockIdx.z * R * C;
  int c0 = blockIdx.x * 64, r0 = blockIdx.y * 64;
  __shared__ u16 T[64][68];
  int tid = threadIdx.x;
#pragma unroll
  for (int p = 0; p < 4; p++) {
    int ch = tid + p * 256;
    int i = ch >> 4, seg = ch & 15;
    us4 v = *(const us4*)&ib[(size_t)(r0 + i) * C + c0 + seg * 4];
    T[i][seg*4+0] = v[0]; T[i][seg*4+1] = v[1];
    T[i][seg*4+2] = v[2]; T[i][seg*4+3] = v[3];
  }
  __syncthreads();
#pragma unroll
  for (int p = 0; p < 4; p++) {
    int ch = tid + p * 256;
    int j = ch >> 4, seg = ch & 15;
    us4 o;
#pragma unroll
    for (int e = 0; e < 4; e++) o[e] = T[seg*4+e][j];
    *(us4*)&ob[(size_t)(c0 + j) * R + r0 + seg * 4] = o;
  }
}

// ---------- small convs via MFMA: fhw[b][r][hw], r<8: w_h conv, r>=8: w_w conv ----------
// A = [16][512] combined weights (fp32->bf16 staged once), B = xbfT rows (K contiguous).
__global__ __launch_bounds__(256) void k_conv16(
    const float* __restrict__ wh, const float* __restrict__ bh,
    const float* __restrict__ ww, const float* __restrict__ bw,
    const u16* __restrict__ XT, u16* __restrict__ Out) {
  __shared__ u16 As[16][520];
  __shared__ float bias_s[16];
  int tid = threadIdx.x;
#pragma unroll
  for (int p = 0; p < 4; p++) {
    int ch = tid + p * 256;               // 1024 chunks of 8 elems
    int r = ch >> 6, seg = ch & 63;
    const float* src = (r < 8) ? &wh[r * 512 + seg * 8] : &ww[(r - 8) * 512 + seg * 8];
    f32x4 v0 = *(const f32x4*)src;
    f32x4 v1 = *(const f32x4*)(src + 4);
    short8 sv;
    sv[0]=f2b(v0[0]); sv[1]=f2b(v0[1]); sv[2]=f2b(v0[2]); sv[3]=f2b(v0[3]);
    sv[4]=f2b(v1[0]); sv[5]=f2b(v1[1]); sv[6]=f2b(v1[2]); sv[7]=f2b(v1[3]);
    *(short8*)&As[r][seg * 8] = sv;
  }
  if (tid < 16) bias_s[tid] = (tid < 8) ? bh[tid] : bw[tid - 8];
  __syncthreads();
  int b = blockIdx.y;
  int nb = blockIdx.x * 128 + (tid >> 6) * 32;   // wave's 32-n strip
  int lane = tid & 63;
  int lr = lane & 15, lg = lane >> 4;
  const u16* Bb = XT + (size_t)b * kCHW;
  f32x4 acc[2] = {};
#pragma unroll 4
  for (int k0 = 0; k0 < 512; k0 += 32) {
    short8 a = *(const short8*)&As[lr][k0 + lg * 8];
    short8 b0 = *(const short8*)&Bb[(size_t)(nb + lr) * 512 + k0 + lg * 8];
    short8 b1 = *(const short8*)&Bb[(size_t)(nb + 16 + lr) * 512 + k0 + lg * 8];
    acc[0] = MFMA(a, b0, acc[0]);
    acc[1] = MFMA(a, b1, acc[1]);
  }
#pragma unroll
  for (int q = 0; q < 2; q++)
#pragma unroll
    for (int r = 0; r < 4; r++) {
      int m = lg * 4 + r;
      Out[((size_t)b * 16 + m) * kHW + nb + q * 16 + lr] = f2b(acc[q][r] + bias_s[m]);
    }
}

// ---------- conv1x1 MFMA GEMM: Out[b][o][n] = sum_c W[o][c]*XT[b][n][c] + bias ----------
__global__ __launch_bounds__(256) void k_gemm_conv(
    const float* __restrict__ A, const u16* __restrict__ BT,
    const float* __restrict__ bias, u16* __restrict__ Out) {
  int b = blockIdx.z;
  int bm = blockIdx.y * 128;   // o
  int bn = blockIdx.x * 128;   // hw
  const u16* Bb = BT + (size_t)b * kCHW;
  __shared__ u16 As[128][72];
  __shared__ u16 Bs[128][72];
  int tid = threadIdx.x;
  int lane = tid & 63, wv = tid >> 6;
  int wr = (wv >> 1) * 64, wc = (wv & 1) * 64;
  int lr = lane & 15, lg = lane >> 4;
  f32x4 acc[4][4] = {};
  for (int k0 = 0; k0 < kC; k0 += 64) {
#pragma unroll
    for (int p = 0; p < 4; p++) {
      int ch = tid + p * 256;
      int row = ch >> 3, seg = ch & 7;
      const float* src = &A[(size_t)(bm + row) * 512 + k0 + seg * 8];
      f32x4 v0 = *(const f32x4*)src;
      f32x4 v1 = *(const f32x4*)(src + 4);
      short8 sv;
      sv[0]=f2b(v0[0]); sv[1]=f2b(v0[1]); sv[2]=f2b(v0[2]); sv[3]=f2b(v0[3]);
      sv[4]=f2b(v1[0]); sv[5]=f2b(v1[1]); sv[6]=f2b(v1[2]); sv[7]=f2b(v1[3]);
      *(short8*)&As[row][seg*8] = sv;
      *(short8*)&Bs[row][seg*8] = *(const short8*)&Bb[(size_t)(bn+row)*512 + k0 + seg*8];
    }
    __syncthreads();
#pragma unroll
    for (int ks = 0; ks < 2; ks++) {
      short8 av[4], bv[4];
#pragma unroll
      for (int m = 0; m < 4; m++) av[m] = *(const short8*)&As[wr + m*16 + lr][ks*32 + lg*8];
#pragma unroll
      for (int n = 0; n < 4; n++) bv[n] = *(const short8*)&Bs[wc + n*16 + lr][ks*32 + lg*8];
#pragma unroll
      for (int m = 0; m < 4; m++)
#pragma unroll
        for (int n = 0; n < 4; n++)
          acc[m][n] = MFMA(av[m], bv[n], acc[m][n]);
    }
    __syncthreads();
  }
  u16* Ob = Out + (size_t)b * kCHW;
#pragma unroll
  for (int m = 0; m < 4; m++)
#pragma unroll
    for (int r = 0; r < 4; r++) {
      int o = bm + wr + m*16 + lg*4 + r;
      float bv_ = bias[o];
#pragma unroll
      for (int n = 0; n < 4; n++)
        Ob[(size_t)o * kHW + bn + wc + n*16 + lr] = f2b(acc[m][n][r] + bv_);
    }
}

// ---------- Gram split-K: part[s][b][i][j] = sum_{n in chunk s} F[b][i][n]F[b][j][n] ----------
__global__ __launch_bounds__(256) void k_gram_sk(const u16* __restrict__ F,
                                                float* __restrict__ part) {
  int z = blockIdx.z;
  int b = z & 3, s = z >> 2;
  int bm = blockIdx.y * 128, bn = blockIdx.x * 128;
  const u16* Fb = F + (size_t)b * kCHW;
  __shared__ u16 As[128][72];
  __shared__ u16 Bs[128][72];
  int tid = threadIdx.x;
  int lane = tid & 63, wv = tid >> 6;
  int wr = (wv >> 1) * 64, wc = (wv & 1) * 64;
  int lr = lane & 15, lg = lane >> 4;
  f32x4 acc[4][4] = {};
  int kbeg = s * 1152;
  for (int k0 = kbeg; k0 < kbeg + 1152; k0 += 64) {
#pragma unroll
    for (int p = 0; p < 4; p++) {
      int ch = tid + p * 256;
      int row = ch >> 3, seg = ch & 7;
      *(short8*)&As[row][seg*8] = *(const short8*)&Fb[(size_t)(bm+row)*kHW + k0 + seg*8];
      *(short8*)&Bs[row][seg*8] = *(const short8*)&Fb[(size_t)(bn+row)*kHW + k0 + seg*8];
    }
    __syncthreads();
#pragma unroll
    for (int ks = 0; ks < 2; ks++) {
      short8 av[4], bv[4];
#pragma unroll
      for (int m = 0; m < 4; m++) av[m] = *(const short8*)&As[wr + m*16 + lr][ks*32 + lg*8];
#pragma unroll
      for (int n = 0; n < 4; n++) bv[n] = *(const short8*)&Bs[wc + n*16 + lr][ks*32 + lg*8];
#pragma unroll
      for (int m = 0; m < 4; m++)
#pragma unroll
        for (int n = 0; n < 4; n++)
          acc[m][n] = MFMA(av[m], bv[n], acc[m][n]);
    }
    __syncthreads();
  }
  float* Pb = part + ((size_t)(s * 4 + b)) * 262144;
#pragma unroll
  for (int m = 0; m < 4; m++)
#pragma unroll
    for (int r = 0; r < 4; r++) {
      int i = bm + wr + m*16 + lg*4 + r;
#pragma unroll
      for (int n = 0; n < 4; n++)
        Pb[(size_t)i * 512 + bn + wc + n*16 + lr] = acc[m][n][r];
    }
}

// ---------- 8-way partial reduce + row softmax over 512 -> gramN fp32 ----------
__global__ __launch_bounds__(256) void k_softmax512r(const float* __restrict__ part,
                                                     float* __restrict__ gramN) {
  int b = blockIdx.x >> 9, i = blockIdx.x & 511;
  int tid = threadIdx.x;
  float v0 = 0.f, v1 = 0.f;
#pragma unroll
  for (int s = 0; s < 8; s++) {
    const float* P = part + ((size_t)(s * 4 + b) * 512 + i) * 512;
    v0 += P[tid];
    v1 += P[tid + 256];
  }
  int wid = tid >> 6, lane = tid & 63;
  float m = fmaxf(v0, v1);
#pragma unroll
  for (int o = 32; o >= 1; o >>= 1) m = fmaxf(m, __shfl_xor(m, o));
  __shared__ float redm[4], reds[4];
  if (lane == 0) redm[wid] = m;
  __syncthreads();
  m = fmaxf(fmaxf(redm[0], redm[1]), fmaxf(redm[2], redm[3]));
  float e0 = expf(v0 - m), e1 = expf(v1 - m);
  float s = e0 + e1;
#pragma unroll
  for (int o = 32; o >= 1; o >>= 1) s += __shfl_xor(s, o);
  if (lane == 0) reds[wid] = s;
  __syncthreads();
  s = reds[0] + reds[1] + reds[2] + reds[3];
  float inv = 1.0f / s;
  float* R = gramN + ((size_t)b * 512 + i) * 512;
  R[tid] = e0 * inv;
  R[tid + 256] = e1 * inv;
}

// ---------- out_C GEMM -> bf16 OutC[b][hw][c] (flat == d_out order) ----------
__global__ __launch_bounds__(256) void k_outc(
    const u16* __restrict__ AT, const u16* __restrict__ Bt,
    const float* __restrict__ gamma, u16* __restrict__ Out) {
  int b = blockIdx.z;
  int bm = blockIdx.y * 128;   // hw
  int bn = blockIdx.x * 128;   // c
  const u16* Ab = AT + (size_t)b * kCHW;
  const u16* Bb = Bt + (size_t)b * 262144;
  __shared__ u16 As[128][72];
  __shared__ u16 Bs[128][72];
  int tid = threadIdx.x;
  int lane = tid & 63, wv = tid >> 6;
  int wr = (wv >> 1) * 64, wc = (wv & 1) * 64;
  int lr = lane & 15, lg = lane >> 4;
  f32x4 acc[4][4] = {};
  for (int k0 = 0; k0 < kC; k0 += 64) {
#pragma unroll
    for (int p = 0; p < 4; p++) {
      int ch = tid + p * 256;
      int row = ch >> 3, seg = ch & 7;
      *(short8*)&As[row][seg*8] = *(const short8*)&Ab[(size_t)(bm+row)*512 + k0 + seg*8];
      *(short8*)&Bs[row][seg*8] = *(const short8*)&Bb[(size_t)(bn+row)*512 + k0 + seg*8];
    }
    __syncthreads();
#pragma unroll
    for (int ks = 0; ks < 2; ks++) {
      short8 av[4], bv[4];
#pragma unroll
      for (int m = 0; m < 4; m++) av[m] = *(const short8*)&As[wr + m*16 + lr][ks*32 + lg*8];
#pragma unroll
      for (int n = 0; n < 4; n++) bv[n] = *(const short8*)&Bs[wc + n*16 + lr][ks*32 + lg*8];
#pragma unroll
      for (int m = 0; m < 4; m++)
#pragma unroll
        for (int n = 0; n < 4; n++)
          acc[m][n] = MFMA(av[m], bv[n], acc[m][n]);
    }
    __syncthreads();
  }
  float g = *gamma;
  u16* Ob = Out + (size_t)b * kCHW;
#pragma unroll
  for (int m = 0; m < 4; m++)
#pragma unroll
    for (int r = 0; r < 4; r++) {
      int mm = bm + wr + m*16 + lg*4 + r;
#pragma unroll
      for (int n = 0; n < 4; n++)
        Ob[(size_t)mm * 512 + bn + wc + n*16 + lr] = f2b(g * acc[m][n][r]);
    }
}

// ---------- E_h -> ccat[b,i,w, j<96] (bf16 in/out) ----------
__global__ __launch_bounds__(256) void k_eh(
    const u16* __restrict__ fhw, u16* __restrict__ Ccat) {
  int b = blockIdx.x / kW, w = blockIdx.x % kW;
  __shared__ float fh[kH][kCr];
  __shared__ float fw[kCr][kH];
  int tid = threadIdx.x;
  for (int l = tid; l < kH * kCr; l += 256) {
    int i = l >> 3, c = l & 7;
    fh[i][c] = b2f(fhw[((size_t)b * 16 + (i & 7)) * kHW + (c * 12 + (i >> 3)) * kW + w]);
    int c2 = l / kH, j = l % kH;
    fw[c2][j] = b2f(fhw[((size_t)b * 16 + 8 + c2) * kHW + j * kW + w]);
  }
  __syncthreads();
  for (int t = tid; t < kH * kH; t += 256) {
    int i = t / kH, j = t % kH;
    float e = 0.f;
#pragma unroll
    for (int c = 0; c < kCr; c++) e += fh[i][c] * fw[c][j];
    if (i == j) e += NEGV;
    Ccat[(((size_t)b * kH + i) * kW + w) * 192 + j] = f2b(e);
  }
}

// ---------- E_w -> ccat[b,h,w, 96+j] (bf16 in/out) ----------
__global__ __launch_bounds__(256) void k_ew(
    const u16* __restrict__ fhw, u16* __restrict__ Ccat) {
  int b = blockIdx.x / kH, h = blockIdx.x % kH;
  __shared__ float fh2[kCr][kW];
  __shared__ float fw2[kCr][kW];
  int tid = threadIdx.x;
  for (int l = tid; l < kCr * kW; l += 256) {
    int c = l / kW, w = l % kW;
    fh2[c][w] = b2f(fhw[((size_t)b * 16 + c) * kHW + h * kW + w]);
    fw2[c][w] = b2f(fhw[((size_t)b * 16 + 8 + c) * kHW + h * kW + w]);
  }
  __syncthreads();
  for (int t = tid; t < kW * kW; t += 256) {
    int w = t / kW, j = t % kW;
    float e = 0.f;
#pragma unroll
    for (int c = 0; c < kCr; c++) e += fh2[c][w] * fw2[c][j];
    Ccat[(((size_t)b * kH + h) * kW + w) * 192 + 96 + j] = f2b(e);
  }
}

// ---------- softmax over 192 (bf16 in-place), one wave per row ----------
__global__ __launch_bounds__(256) void k_softmax192(u16* __restrict__ Ccat) {
  int r = blockIdx.x * 4 + (threadIdx.x >> 6);
  int lane = threadIdx.x & 63;
  u16* R = Ccat + (size_t)r * 192;
  float a = b2f(R[lane]), b = b2f(R[lane + 64]), c = b2f(R[lane + 128]);
  float m = fmaxf(a, fmaxf(b, c));
#pragma unroll
  for (int o = 32; o >= 1; o >>= 1) m = fmaxf(m, __shfl_xor(m, o));
  float ea = expf(a - m), eb = expf(b - m), ec = expf(c - m);
  float s = ea + eb + ec;
#pragma unroll
  for (int o = 32; o >= 1; o >>= 1) s += __shfl_xor(s, o);
  float inv = 1.0f / s;
  R[lane] = f2b(ea * inv);
  R[lane + 64] = f2b(eb * inv);
  R[lane + 128] = f2b(ec * inv);
}

// ---------- per-(b,c) 96x96 plane transpose (bf16) ----------
__global__ __launch_bounds__(256) void k_tr_plane(const u16* __restrict__ in,
                                                  u16* __restrict__ out) {
  size_t pl = blockIdx.x;
  const u16* ib = in + pl * 9216;
  u16* ob = out + pl * 9216;
  __shared__ u16 T[96][100];
  int tid = threadIdx.x;
  for (int ch = tid; ch < 96 * 24; ch += 256) {
    int i = ch / 24, seg = ch % 24;
    *(us4*)&T[i][seg*4] = *(const us4*)&ib[i*96 + seg*4];
  }
  __syncthreads();
  for (int ch = tid; ch < 96 * 24; ch += 256) {
    int j = ch / 24, seg = ch % 24;
    us4 o;
#pragma unroll
    for (int e = 0; e < 4; e++) o[e] = T[seg*4+e][j];
    *(us4*)&ob[j*96 + seg*4] = o;
  }
}

// ---------- H-path: per (b,w): HT[b][c][w][h] = alpha * sum_j AT[c][j] att[h][j] ----------
__global__ __launch_bounds__(512) void k_final_h(
    const u16* __restrict__ AT,    // f_chaT [B][512][96(w)][96(j=h)]
    const u16* __restrict__ att,   // ccat bf16 [B][96][96][192]
    const float* __restrict__ alpha,
    u16* __restrict__ OutHT) {
  int b = blockIdx.x / 96, w = blockIdx.x % 96;
  __shared__ u16 Bs[96][104];
  int tid = threadIdx.x;
  for (int ch = tid; ch < 1152; ch += 512) {
    int h = ch / 12, seg = ch % 12;
    *(short8*)&Bs[h][seg*8] =
        *(const short8*)&att[(((size_t)b*96 + h)*96 + w)*192 + seg*8];
  }
  __syncthreads();
  int lane = tid & 63, wv = tid >> 6;
  int lr = lane & 15, lg = lane >> 4;
  int c0 = wv * 64;
  const u16* Ab = AT + ((size_t)b*512 + c0)*kHW + w*96;
  f32x4 acc[4][6] = {};
#pragma unroll
  for (int ks = 0; ks < 3; ks++) {
    short8 av[4];
#pragma unroll
    for (int m = 0; m < 4; m++)
      av[m] = *(const short8*)&Ab[(size_t)(m*16 + lr)*kHW + ks*32 + lg*8];
#pragma unroll
    for (int n = 0; n < 6; n++) {
      short8 bv = *(const short8*)&Bs[n*16 + lr][ks*32 + lg*8];
#pragma unroll
      for (int m = 0; m < 4; m++) acc[m][n] = MFMA(av[m], bv, acc[m][n]);
    }
  }
  float al = *alpha;
  u16* Ob = OutHT + ((size_t)b*512 + c0)*kHW + w*96;
#pragma unroll
  for (int m = 0; m < 4; m++)
#pragma unroll
    for (int r = 0; r < 4; r++) {
      size_t crow = (size_t)(m*16 + lg*4 + r) * kHW;
#pragma unroll
      for (int n = 0; n < 6; n++)
        Ob[crow + n*16 + lr] = f2b(al * acc[m][n][r]);
    }
}

// ---------- W-path: per (b,h): OutW[b][c][h][w] = beta * sum_j A[c][j] att[w][96+j] ----------
__global__ __launch_bounds__(512) void k_final_w(
    const u16* __restrict__ A,     // f_cha [B][512][96(h)][96(j=w)]
    const u16* __restrict__ att,
    const float* __restrict__ beta,
    u16* __restrict__ OutW) {
  int b = blockIdx.x / 96, h = blockIdx.x % 96;
  __shared__ u16 Bs[96][104];
  int tid = threadIdx.x;
  for (int ch = tid; ch < 1152; ch += 512) {
    int wr_ = ch / 12, seg = ch % 12;
    *(short8*)&Bs[wr_][seg*8] =
        *(const short8*)&att[(((size_t)b*96 + h)*96 + wr_)*192 + 96 + seg*8];
  }
  __syncthreads();
  int lane = tid & 63, wv = tid >> 6;
  int lr = lane & 15, lg = lane >> 4;
  int c0 = wv * 64;
  const u16* Ab = A + ((size_t)b*512 + c0)*kHW + h*96;
  f32x4 acc[4][6] = {};
#pragma unroll
  for (int ks = 0; ks < 3; ks++) {
    short8 av[4];
#pragma unroll
    for (int m = 0; m < 4; m++)
      av[m] = *(const short8*)&Ab[(size_t)(m*16 + lr)*kHW + ks*32 + lg*8];
#pragma unroll
    for (int n = 0; n < 6; n++) {
      short8 bv = *(const short8*)&Bs[n*16 + lr][ks*32 + lg*8];
#pragma unroll
      for (int m = 0; m < 4; m++) acc[m][n] = MFMA(av[m], bv, acc[m][n]);
    }
  }
  float be = *beta;
  u16* Ob = OutW + ((size_t)b*512 + c0)*kHW + h*96;
#pragma unroll
  for (int m = 0; m < 4; m++)
#pragma unroll
    for (int r = 0; r < 4; r++) {
      size_t crow = (size_t)(m*16 + lg*4 + r) * kHW;
#pragma unroll
      for (int n = 0; n < 6; n++)
        Ob[crow + n*16 + lr] = f2b(be * acc[m][n][r]);
    }
}

// ---------- merge: out = x + OutC + OutW + HT^T(per plane) ----------
__global__ __launch_bounds__(256) void k_merge(
    const float* __restrict__ x, const u16* __restrict__ OutC,
    const u16* __restrict__ OutW, const u16* __restrict__ HT,
    float* __restrict__ out) {
  size_t pl = blockIdx.x;
  const u16* hb = HT + pl * 9216;
  __shared__ u16 T[96][100];
  int tid = threadIdx.x;
  for (int ch = tid; ch < 96 * 24; ch += 256) {
    int i = ch / 24, seg = ch % 24;
    *(us4*)&T[i][seg*4] = *(const us4*)&hb[i*96 + seg*4];
  }
  __syncthreads();
  const float* xb = x + pl * 9216;
  const u16* cb = OutC + pl * 9216;
  const u16* wb = OutW + pl * 9216;
  float* ob = out + pl * 9216;
  for (int ch = tid; ch < 2304; ch += 256) {
    int i4 = ch * 4;
    int h = i4 / 96, w = i4 % 96;
    f32x4 xv = *(const f32x4*)&xb[i4];
    us4 cv = *(const us4*)&cb[i4];
    us4 wv = *(const us4*)&wb[i4];
    f32x4 o;
#pragma unroll
    for (int e = 0; e < 4; e++)
      o[e] = xv[e] + b2f(cv[e]) + b2f(wv[e]) + b2f(T[w + e][h]);
    *(f32x4*)&ob[i4] = o;
  }
}

extern "C" void kernel_launch(void* const* d_in, const int* in_sizes, int n_in,
                              void* d_out, int out_size, void* d_ws, size_t ws_size,
                              hipStream_t stream) {
  const float* x     = (const float*)d_in[0];
  const float* w_h   = (const float*)d_in[1];
  const float* b_h   = (const float*)d_in[2];
  const float* w_w   = (const float*)d_in[3];
  const float* b_w   = (const float*)d_in[4];
  const float* w_c   = (const float*)d_in[5];
  const float* b_c   = (const float*)d_in[6];
  const float* w_o   = (const float*)d_in[7];
  const float* b_o   = (const float*)d_in[8];
  const float* alpha = (const float*)d_in[9];
  const float* beta  = (const float*)d_in[10];
  const float* gamma = (const float*)d_in[11];
  float* out = (float*)d_out;

  // Region plan. R = 37748736 (one [B][512][9216] bf16 buffer).
  //  A [0,R):   xbfT (1-4) / gram partials 33.5MB (6-7) / f_chaT (13-14) / OutW (15-16)
  //  B [R,2R):  f_ch (3-6) / OutC (9-16)
  //  C [2R,3R): f_chT (5-9) / HT (14-16)
  //  D [3R,4R): f_cha (4-15)
  //  E: fhw bf16 [B][16][9216] (2-11)
  //  F: gramN(4.19M,7-8)+affT(2.10M,8-9) overlaid by ccat 14.16M (10-15)
  const size_t R = 37748736;
  char* p = (char*)d_ws;
  u16*   xbfT   = (u16*)(p);
  float* part   = (float*)(p);
  u16*   f_chaT = (u16*)(p);
  u16*   outW   = (u16*)(p);
  u16*   f_ch   = (u16*)(p + R);
  u16*   outC   = (u16*)(p + R);
  u16*   f_chT  = (u16*)(p + 2 * R);
  u16*   outHT  = (u16*)(p + 2 * R);
  u16*   f_cha  = (u16*)(p + 3 * R);
  u16*   fhw    = (u16*)(p + 4 * R);
  char*  F      = p + 4 * R + 2359296;
  float* gramN  = (float*)F;
  u16*   affT   = (u16*)(F + 4194304);
  u16*   ccat   = (u16*)F;

  k_cvt_T<<<dim3(144, 8, 4), 256, 0, stream>>>(x, xbfT, 512, 9216);
  k_conv16<<<dim3(72, 4), 256, 0, stream>>>(w_h, b_h, w_w, b_w, xbfT, fhw);
  k_gemm_conv<<<dim3(72, 4, 4), 256, 0, stream>>>(w_c, xbfT, b_c, f_ch);
  k_gemm_conv<<<dim3(72, 4, 4), 256, 0, stream>>>(w_o, xbfT, b_o, f_cha);
  k_trT_bf<<<dim3(144, 8, 4), 256, 0, stream>>>(f_ch, f_chT, 512, 9216);
  k_gram_sk<<<dim3(4, 4, 32), 256, 0, stream>>>(f_ch, part);
  k_softmax512r<<<2048, 256, 0, stream>>>(part, gramN);
  k_cvt_T<<<dim3(8, 8, 4), 256, 0, stream>>>(gramN, affT, 512, 512);
  k_outc<<<dim3(4, 72, 4), 256, 0, stream>>>(f_chT, affT, gamma, outC);
  k_eh<<<384, 256, 0, stream>>>(fhw, ccat);
  k_ew<<<384, 256, 0, stream>>>(fhw, ccat);
  k_softmax192<<<9216, 256, 0, stream>>>(ccat);
  k_tr_plane<<<2048, 256, 0, stream>>>(f_cha, f_chaT);
  k_final_h<<<384, 512, 0, stream>>>(f_chaT, ccat, alpha, outHT);
  k_final_w<<<384, 512, 0, stream>>>(f_cha, ccat, beta, outW);
  k_merge<<<2048, 256, 0, stream>>>(x, outC, outW, outHT, out);
}

// Round 5
// 310.734 us; speedup vs baseline: 8.8781x; 1.1010x over previous
//
#include <hip/hip_runtime.h>

typedef __attribute__((ext_vector_type(8))) short short8;
typedef __attribute__((ext_vector_type(4))) float f32x4;
typedef __attribute__((ext_vector_type(4))) unsigned short us4;
typedef unsigned short u16;

#define kB 4
#define kC 512
#define kCr 8
#define kH 96
#define kW 96
#define kHW 9216
#define kCHW 4718592
#define NEGV -1e9f

__device__ __forceinline__ u16 f2b(float f) {
  union { float f; unsigned u; } v; v.f = f;
  unsigned r = v.u + 0x7fff + ((v.u >> 16) & 1);
  return (u16)(r >> 16);
}
__device__ __forceinline__ float b2f(u16 h) {
  union { unsigned u; float f; } v; v.u = ((unsigned)h) << 16;
  return v.f;
}
#define MFMA(a, b, c) __builtin_amdgcn_mfma_f32_16x16x32_bf16(a, b, c, 0, 0, 0)

// async global->LDS, 16B per lane. LDS dest must be wave-uniform-base + lane*16.
__device__ __forceinline__ void gl16(const u16* g, u16* l) {
  __builtin_amdgcn_global_load_lds(
      (const __attribute__((address_space(1))) void*)g,
      (__attribute__((address_space(3))) void*)l, 16, 0, 0);
}

// ---------- fp32 [R][C] -> bf16 [C][R] transpose-convert, 64x64 tiles ----------
__global__ __launch_bounds__(256) void k_cvt_T(const float* __restrict__ in,
                                               u16* __restrict__ out,
                                               int R, int C) {
  const float* ib = in + (size_t)blockIdx.z * R * C;
  u16* ob = out + (size_t)blockIdx.z * R * C;
  int c0 = blockIdx.x * 64, r0 = blockIdx.y * 64;
  __shared__ u16 T[64][68];
  int tid = threadIdx.x;
#pragma unroll
  for (int p = 0; p < 4; p++) {
    int ch = tid + p * 256;
    int i = ch >> 4, seg = ch & 15;
    f32x4 v = *(const f32x4*)&ib[(size_t)(r0 + i) * C + c0 + seg * 4];
    T[i][seg*4+0] = f2b(v[0]); T[i][seg*4+1] = f2b(v[1]);
    T[i][seg*4+2] = f2b(v[2]); T[i][seg*4+3] = f2b(v[3]);
  }
  __syncthreads();
#pragma unroll
  for (int p = 0; p < 4; p++) {
    int ch = tid + p * 256;
    int j = ch >> 4, seg = ch & 15;
    us4 o;
#pragma unroll
    for (int e = 0; e < 4; e++) o[e] = T[seg*4+e][j];
    *(us4*)&ob[(size_t)(c0 + j) * R + r0 + seg * 4] = o;
  }
}

// ---------- bf16 [R][C] -> bf16 [C][R] transpose, 64x64 tiles ----------
__global__ __launch_bounds__(256) void k_trT_bf(const u16* __restrict__ in,
                                                u16* __restrict__ out,
                                                int R, int C) {
  const u16* ib = in + (size_t)blockIdx.z * R * C;
  u16* ob = out + (size_t)blockIdx.z * R * C;
  int c0 = blockIdx.x * 64, r0 = blockIdx.y * 64;
  __shared__ u16 T[64][68];
  int tid = threadIdx.x;
#pragma unroll
  for (int p = 0; p < 4; p++) {
    int ch = tid + p * 256;
    int i = ch >> 4, seg = ch & 15;
    us4 v = *(const us4*)&ib[(size_t)(r0 + i) * C + c0 + seg * 4];
    T[i][seg*4+0] = v[0]; T[i][seg*4+1] = v[1];
    T[i][seg*4+2] = v[2]; T[i][seg*4+3] = v[3];
  }
  __syncthreads();
#pragma unroll
  for (int p = 0; p < 4; p++) {
    int ch = tid + p * 256;
    int j = ch >> 4, seg = ch & 15;
    us4 o;
#pragma unroll
    for (int e = 0; e < 4; e++) o[e] = T[seg*4+e][j];
    *(us4*)&ob[(size_t)(c0 + j) * R + r0 + seg * 4] = o;
  }
}

// ---------- weights fp32 -> bf16: wco[0:512]=w_c, wco[512:1024]=w_o ----------
__global__ __launch_bounds__(256) void k_cvtw(const float* __restrict__ wc,
                                              const float* __restrict__ wo,
                                              u16* __restrict__ wco) {
  int i = blockIdx.x * 256 + threadIdx.x;   // 131072 chunks of 4 floats
  const float* src = (i < 65536) ? &wc[(size_t)i * 4] : &wo[(size_t)(i - 65536) * 4];
  f32x4 v = *(const f32x4*)src;
  us4 o;
  o[0] = f2b(v[0]); o[1] = f2b(v[1]); o[2] = f2b(v[2]); o[3] = f2b(v[3]);
  ((us4*)wco)[i] = o;
}

// ---------- small convs via MFMA: fhw[b][r][hw], r<8: w_h conv, r>=8: w_w conv ----------
__global__ __launch_bounds__(256) void k_conv16(
    const float* __restrict__ wh, const float* __restrict__ bh,
    const float* __restrict__ ww, const float* __restrict__ bw,
    const u16* __restrict__ XT, u16* __restrict__ Out) {
  __shared__ u16 As[16][520];
  __shared__ float bias_s[16];
  int tid = threadIdx.x;
#pragma unroll
  for (int p = 0; p < 4; p++) {
    int ch = tid + p * 256;               // 1024 chunks of 8 elems
    int r = ch >> 6, seg = ch & 63;
    const float* src = (r < 8) ? &wh[r * 512 + seg * 8] : &ww[(r - 8) * 512 + seg * 8];
    f32x4 v0 = *(const f32x4*)src;
    f32x4 v1 = *(const f32x4*)(src + 4);
    short8 sv;
    sv[0]=f2b(v0[0]); sv[1]=f2b(v0[1]); sv[2]=f2b(v0[2]); sv[3]=f2b(v0[3]);
    sv[4]=f2b(v1[0]); sv[5]=f2b(v1[1]); sv[6]=f2b(v1[2]); sv[7]=f2b(v1[3]);
    *(short8*)&As[r][seg * 8] = sv;
  }
  if (tid < 16) bias_s[tid] = (tid < 8) ? bh[tid] : bw[tid - 8];
  __syncthreads();
  int b = blockIdx.y;
  int nb = blockIdx.x * 128 + (tid >> 6) * 32;   // wave's 32-n strip
  int lane = tid & 63;
  int lr = lane & 15, lg = lane >> 4;
  const u16* Bb = XT + (size_t)b * kCHW;
  f32x4 acc[2] = {};
#pragma unroll 4
  for (int k0 = 0; k0 < 512; k0 += 32) {
    short8 a = *(const short8*)&As[lr][k0 + lg * 8];
    short8 b0 = *(const short8*)&Bb[(size_t)(nb + lr) * 512 + k0 + lg * 8];
    short8 b1 = *(const short8*)&Bb[(size_t)(nb + 16 + lr) * 512 + k0 + lg * 8];
    acc[0] = MFMA(a, b0, acc[0]);
    acc[1] = MFMA(a, b1, acc[1]);
  }
#pragma unroll
  for (int q = 0; q < 2; q++)
#pragma unroll
    for (int r = 0; r < 4; r++) {
      int m = lg * 4 + r;
      Out[((size_t)b * 16 + m) * kHW + nb + q * 16 + lr] = f2b(acc[q][r] + bias_s[m]);
    }
}

// ======== shared 2-phase pipelined 128x128 GEMM body (A.B^T, K-major rows) ======
// LDS linear [2][128][64], gload_lds staging with XOR chunk-swizzle (cc ^= row&7)
// applied to the per-lane GLOBAL address on stage and to the ds_read chunk on read.
#define GEMM_PROLOG()                                                      \
  int tid = threadIdx.x;                                                   \
  int lane = tid & 63, wv = tid >> 6;                                      \
  int wr = (wv >> 1) * 64, wc = (wv & 1) * 64;                             \
  int lr = lane & 15, lg = lane >> 4;                                      \
  f32x4 acc[4][4] = {};

#define STAGE(bufv, kk)                                                    \
  {                                                                        \
    _Pragma("unroll")                                                      \
    for (int p = 0; p < 4; p++) {                                          \
      int ch = tid + p * 256;                                              \
      int row = ch >> 3, cc = ch & 7;                                      \
      int sc = (cc ^ (row & 7)) * 8;                                       \
      gl16(&Asrc[(size_t)(bm + row) * LDA + (kk) + sc], &As[bufv][row][cc * 8]); \
      gl16(&Bsrc[(size_t)(bn + row) * LDB + (kk) + sc], &Bs[bufv][row][cc * 8]); \
    }                                                                      \
  }

#define COMPUTE(bufv)                                                      \
  {                                                                        \
    _Pragma("unroll")                                                      \
    for (int ks = 0; ks < 2; ks++) {                                       \
      int ca = ((ks * 4 + lg) ^ (lr & 7)) * 8;                             \
      short8 av[4], bv[4];                                                 \
      _Pragma("unroll")                                                    \
      for (int m = 0; m < 4; m++)                                          \
        av[m] = *(const short8*)&As[bufv][wr + m * 16 + lr][ca];           \
      _Pragma("unroll")                                                    \
      for (int n = 0; n < 4; n++)                                          \
        bv[n] = *(const short8*)&Bs[bufv][wc + n * 16 + lr][ca];           \
      _Pragma("unroll")                                                    \
      for (int m = 0; m < 4; m++)                                          \
        _Pragma("unroll")                                                  \
        for (int n = 0; n < 4; n++)                                        \
          acc[m][n] = MFMA(av[m], bv[n], acc[m][n]);                       \
    }                                                                      \
  }

// ---------- merged conv1x1 GEMM: M=1024 (w_c rows then w_o rows) ----------
__global__ __launch_bounds__(256) void k_gemm_conv2(
    const u16* __restrict__ wco, const u16* __restrict__ BT,
    const float* __restrict__ b_c, const float* __restrict__ b_o,
    u16* __restrict__ f_ch, u16* __restrict__ f_cha) {
  __shared__ u16 As[2][128][64];
  __shared__ u16 Bs[2][128][64];
  int b = blockIdx.z;
  int bm = blockIdx.y * 128;   // o in [0,1024)
  int bn = blockIdx.x * 128;   // hw
  const u16* Asrc = wco;
  const u16* Bsrc = BT + (size_t)b * kCHW;
  const int LDA = 512, LDB = 512;
  GEMM_PROLOG();
  STAGE(0, 0);
  __syncthreads();
  int cur = 0;
#pragma unroll 1
  for (int t = 0; t < 7; t++) {
    STAGE(cur ^ 1, (t + 1) * 64);
    COMPUTE(cur);
    __syncthreads();
    cur ^= 1;
  }
  COMPUTE(cur);
  const float* biasp = (bm < 512) ? (b_c + bm) : (b_o + bm - 512);
  u16* Ob = (bm < 512) ? (f_ch + (size_t)b * kCHW + (size_t)bm * kHW)
                       : (f_cha + (size_t)b * kCHW + (size_t)(bm - 512) * kHW);
#pragma unroll
  for (int m = 0; m < 4; m++)
#pragma unroll
    for (int r = 0; r < 4; r++) {
      int ol = wr + m * 16 + lg * 4 + r;
      float bv_ = biasp[ol];
#pragma unroll
      for (int n = 0; n < 4; n++)
        Ob[(size_t)ol * kHW + bn + wc + n * 16 + lr] = f2b(acc[m][n][r] + bv_);
    }
}

// ---------- Gram split-K (2-phase): part[s][b] += F F^T over K-chunk ----------
__global__ __launch_bounds__(256) void k_gram_sk(const u16* __restrict__ F,
                                                 float* __restrict__ part) {
  __shared__ u16 As[2][128][64];
  __shared__ u16 Bs[2][128][64];
  int z = blockIdx.z;
  int b = z & 3, s = z >> 2;
  int bm = blockIdx.y * 128, bn = blockIdx.x * 128;
  const u16* Asrc = F + (size_t)b * kCHW;
  const u16* Bsrc = Asrc;
  const int LDA = kHW, LDB = kHW;
  int kbeg = s * 1152;
  GEMM_PROLOG();
  STAGE(0, kbeg);
  __syncthreads();
  int cur = 0;
#pragma unroll 1
  for (int t = 0; t < 17; t++) {
    STAGE(cur ^ 1, kbeg + (t + 1) * 64);
    COMPUTE(cur);
    __syncthreads();
    cur ^= 1;
  }
  COMPUTE(cur);
  float* Pb = part + ((size_t)(s * 4 + b)) * 262144;
#pragma unroll
  for (int m = 0; m < 4; m++)
#pragma unroll
    for (int r = 0; r < 4; r++) {
      int i = bm + wr + m * 16 + lg * 4 + r;
#pragma unroll
      for (int n = 0; n < 4; n++)
        Pb[(size_t)i * 512 + bn + wc + n * 16 + lr] = acc[m][n][r];
    }
}

// ---------- out_C GEMM (2-phase) -> bf16 OutC[b][hw][c] (flat == d_out order) ----------
__global__ __launch_bounds__(256) void k_outc(
    const u16* __restrict__ AT, const u16* __restrict__ Bt,
    const float* __restrict__ gamma, u16* __restrict__ Out) {
  __shared__ u16 As[2][128][64];
  __shared__ u16 Bs[2][128][64];
  int b = blockIdx.z;
  int bm = blockIdx.y * 128;   // hw
  int bn = blockIdx.x * 128;   // c
  const u16* Asrc = AT + (size_t)b * kCHW;
  const u16* Bsrc = Bt + (size_t)b * 262144;
  const int LDA = 512, LDB = 512;
  GEMM_PROLOG();
  STAGE(0, 0);
  __syncthreads();
  int cur = 0;
#pragma unroll 1
  for (int t = 0; t < 7; t++) {
    STAGE(cur ^ 1, (t + 1) * 64);
    COMPUTE(cur);
    __syncthreads();
    cur ^= 1;
  }
  COMPUTE(cur);
  float g = *gamma;
  u16* Ob = Out + (size_t)b * kCHW;
#pragma unroll
  for (int m = 0; m < 4; m++)
#pragma unroll
    for (int r = 0; r < 4; r++) {
      int mm = bm + wr + m * 16 + lg * 4 + r;
#pragma unroll
      for (int n = 0; n < 4; n++)
        Ob[(size_t)mm * 512 + bn + wc + n * 16 + lr] = f2b(g * acc[m][n][r]);
    }
}

// ---------- 8-way partial reduce + row softmax over 512 -> gramN fp32 ----------
__global__ __launch_bounds__(256) void k_softmax512r(const float* __restrict__ part,
                                                     float* __restrict__ gramN) {
  int b = blockIdx.x >> 9, i = blockIdx.x & 511;
  int tid = threadIdx.x;
  float v0 = 0.f, v1 = 0.f;
#pragma unroll
  for (int s = 0; s < 8; s++) {
    const float* P = part + ((size_t)(s * 4 + b) * 512 + i) * 512;
    v0 += P[tid];
    v1 += P[tid + 256];
  }
  int wid = tid >> 6, lane = tid & 63;
  float m = fmaxf(v0, v1);
#pragma unroll
  for (int o = 32; o >= 1; o >>= 1) m = fmaxf(m, __shfl_xor(m, o));
  __shared__ float redm[4], reds[4];
  if (lane == 0) redm[wid] = m;
  __syncthreads();
  m = fmaxf(fmaxf(redm[0], redm[1]), fmaxf(redm[2], redm[3]));
  float e0 = expf(v0 - m), e1 = expf(v1 - m);
  float s = e0 + e1;
#pragma unroll
  for (int o = 32; o >= 1; o >>= 1) s += __shfl_xor(s, o);
  if (lane == 0) reds[wid] = s;
  __syncthreads();
  s = reds[0] + reds[1] + reds[2] + reds[3];
  float inv = 1.0f / s;
  float* R = gramN + ((size_t)b * 512 + i) * 512;
  R[tid] = e0 * inv;
  R[tid + 256] = e1 * inv;
}

// ---------- E_h -> ccat[b,i,w, j<96] (bf16 in/out) ----------
__global__ __launch_bounds__(256) void k_eh(
    const u16* __restrict__ fhw, u16* __restrict__ Ccat) {
  int b = blockIdx.x / kW, w = blockIdx.x % kW;
  __shared__ float fh[kH][kCr];
  __shared__ float fw[kCr][kH];
  int tid = threadIdx.x;
  for (int l = tid; l < kH * kCr; l += 256) {
    int i = l >> 3, c = l & 7;
    fh[i][c] = b2f(fhw[((size_t)b * 16 + (i & 7)) * kHW + (c * 12 + (i >> 3)) * kW + w]);
    int c2 = l / kH, j = l % kH;
    fw[c2][j] = b2f(fhw[((size_t)b * 16 + 8 + c2) * kHW + j * kW + w]);
  }
  __syncthreads();
  for (int t = tid; t < kH * kH; t += 256) {
    int i = t / kH, j = t % kH;
    float e = 0.f;
#pragma unroll
    for (int c = 0; c < kCr; c++) e += fh[i][c] * fw[c][j];
    if (i == j) e += NEGV;
    Ccat[(((size_t)b * kH + i) * kW + w) * 192 + j] = f2b(e);
  }
}

// ---------- E_w -> ccat[b,h,w, 96+j] (bf16 in/out) ----------
__global__ __launch_bounds__(256) void k_ew(
    const u16* __restrict__ fhw, u16* __restrict__ Ccat) {
  int b = blockIdx.x / kH, h = blockIdx.x % kH;
  __shared__ float fh2[kCr][kW];
  __shared__ float fw2[kCr][kW];
  int tid = threadIdx.x;
  for (int l = tid; l < kCr * kW; l += 256) {
    int c = l / kW, w = l % kW;
    fh2[c][w] = b2f(fhw[((size_t)b * 16 + c) * kHW + h * kW + w]);
    fw2[c][w] = b2f(fhw[((size_t)b * 16 + 8 + c) * kHW + h * kW + w]);
  }
  __syncthreads();
  for (int t = tid; t < kW * kW; t += 256) {
    int w = t / kW, j = t % kW;
    float e = 0.f;
#pragma unroll
    for (int c = 0; c < kCr; c++) e += fh2[c][w] * fw2[c][j];
    Ccat[(((size_t)b * kH + h) * kW + w) * 192 + 96 + j] = f2b(e);
  }
}

// ---------- softmax over 192 (bf16 in-place), one wave per row ----------
__global__ __launch_bounds__(256) void k_softmax192(u16* __restrict__ Ccat) {
  int r = blockIdx.x * 4 + (threadIdx.x >> 6);
  int lane = threadIdx.x & 63;
  u16* R = Ccat + (size_t)r * 192;
  float a = b2f(R[lane]), b = b2f(R[lane + 64]), c = b2f(R[lane + 128]);
  float m = fmaxf(a, fmaxf(b, c));
#pragma unroll
  for (int o = 32; o >= 1; o >>= 1) m = fmaxf(m, __shfl_xor(m, o));
  float ea = expf(a - m), eb = expf(b - m), ec = expf(c - m);
  float s = ea + eb + ec;
#pragma unroll
  for (int o = 32; o >= 1; o >>= 1) s += __shfl_xor(s, o);
  float inv = 1.0f / s;
  R[lane] = f2b(ea * inv);
  R[lane + 64] = f2b(eb * inv);
  R[lane + 128] = f2b(ec * inv);
}

// ---------- per-(b,c) 96x96 plane transpose (bf16) ----------
__global__ __launch_bounds__(256) void k_tr_plane(const u16* __restrict__ in,
                                                  u16* __restrict__ out) {
  size_t pl = blockIdx.x;
  const u16* ib = in + pl * 9216;
  u16* ob = out + pl * 9216;
  __shared__ u16 T[96][100];
  int tid = threadIdx.x;
  for (int ch = tid; ch < 96 * 24; ch += 256) {
    int i = ch / 24, seg = ch % 24;
    *(us4*)&T[i][seg*4] = *(const us4*)&ib[i*96 + seg*4];
  }
  __syncthreads();
  for (int ch = tid; ch < 96 * 24; ch += 256) {
    int j = ch / 24, seg = ch % 24;
    us4 o;
#pragma unroll
    for (int e = 0; e < 4; e++) o[e] = T[seg*4+e][j];
    *(us4*)&ob[j*96 + seg*4] = o;
  }
}

// ---------- H-path: per (b,w): HT[b][c][w][h] = alpha * sum_j AT[c][j] att[h][j] ----------
__global__ __launch_bounds__(512) void k_final_h(
    const u16* __restrict__ AT,    // f_chaT [B][512][96(w)][96(j=h)]
    const u16* __restrict__ att,   // ccat bf16 [B][96][96][192]
    const float* __restrict__ alpha,
    u16* __restrict__ OutHT) {
  int b = blockIdx.x / 96, w = blockIdx.x % 96;
  __shared__ u16 Bs[96][104];
  int tid = threadIdx.x;
  for (int ch = tid; ch < 1152; ch += 512) {
    int h = ch / 12, seg = ch % 12;
    *(short8*)&Bs[h][seg*8] =
        *(const short8*)&att[(((size_t)b*96 + h)*96 + w)*192 + seg*8];
  }
  __syncthreads();
  int lane = tid & 63, wv = tid >> 6;
  int lr = lane & 15, lg = lane >> 4;
  int c0 = wv * 64;
  const u16* Ab = AT + ((size_t)b*512 + c0)*kHW + w*96;
  f32x4 acc[4][6] = {};
#pragma unroll
  for (int ks = 0; ks < 3; ks++) {
    short8 av[4];
#pragma unroll
    for (int m = 0; m < 4; m++)
      av[m] = *(const short8*)&Ab[(size_t)(m*16 + lr)*kHW + ks*32 + lg*8];
#pragma unroll
    for (int n = 0; n < 6; n++) {
      short8 bv = *(const short8*)&Bs[n*16 + lr][ks*32 + lg*8];
#pragma unroll
      for (int m = 0; m < 4; m++) acc[m][n] = MFMA(av[m], bv, acc[m][n]);
    }
  }
  float al = *alpha;
  u16* Ob = OutHT + ((size_t)b*512 + c0)*kHW + w*96;
#pragma unroll
  for (int m = 0; m < 4; m++)
#pragma unroll
    for (int r = 0; r < 4; r++) {
      size_t crow = (size_t)(m*16 + lg*4 + r) * kHW;
#pragma unroll
      for (int n = 0; n < 6; n++)
        Ob[crow + n*16 + lr] = f2b(al * acc[m][n][r]);
    }
}

// ---------- W-path: per (b,h): OutW[b][c][h][w] = beta * sum_j A[c][j] att[w][96+j] ----------
__global__ __launch_bounds__(512) void k_final_w(
    const u16* __restrict__ A,     // f_cha [B][512][96(h)][96(j=w)]
    const u16* __restrict__ att,
    const float* __restrict__ beta,
    u16* __restrict__ OutW) {
  int b = blockIdx.x / 96, h = blockIdx.x % 96;
  __shared__ u16 Bs[96][104];
  int tid = threadIdx.x;
  for (int ch = tid; ch < 1152; ch += 512) {
    int wr_ = ch / 12, seg = ch % 12;
    *(short8*)&Bs[wr_][seg*8] =
        *(const short8*)&att[(((size_t)b*96 + h)*96 + wr_)*192 + 96 + seg*8];
  }
  __syncthreads();
  int lane = tid & 63, wv = tid >> 6;
  int lr = lane & 15, lg = lane >> 4;
  int c0 = wv * 64;
  const u16* Ab = A + ((size_t)b*512 + c0)*kHW + h*96;
  f32x4 acc[4][6] = {};
#pragma unroll
  for (int ks = 0; ks < 3; ks++) {
    short8 av[4];
#pragma unroll
    for (int m = 0; m < 4; m++)
      av[m] = *(const short8*)&Ab[(size_t)(m*16 + lr)*kHW + ks*32 + lg*8];
#pragma unroll
    for (int n = 0; n < 6; n++) {
      short8 bv = *(const short8*)&Bs[n*16 + lr][ks*32 + lg*8];
#pragma unroll
      for (int m = 0; m < 4; m++) acc[m][n] = MFMA(av[m], bv, acc[m][n]);
    }
  }
  float be = *beta;
  u16* Ob = OutW + ((size_t)b*512 + c0)*kHW + h*96;
#pragma unroll
  for (int m = 0; m < 4; m++)
#pragma unroll
    for (int r = 0; r < 4; r++) {
      size_t crow = (size_t)(m*16 + lg*4 + r) * kHW;
#pragma unroll
      for (int n = 0; n < 6; n++)
        Ob[crow + n*16 + lr] = f2b(be * acc[m][n][r]);
    }
}

// ---------- merge: out = x + OutC + OutW + HT^T(per plane) ----------
__global__ __launch_bounds__(256) void k_merge(
    const float* __restrict__ x, const u16* __restrict__ OutC,
    const u16* __restrict__ OutW, const u16* __restrict__ HT,
    float* __restrict__ out) {
  size_t pl = blockIdx.x;
  const u16* hb = HT + pl * 9216;
  __shared__ u16 T[96][100];
  int tid = threadIdx.x;
  for (int ch = tid; ch < 96 * 24; ch += 256) {
    int i = ch / 24, seg = ch % 24;
    *(us4*)&T[i][seg*4] = *(const us4*)&hb[i*96 + seg*4];
  }
  __syncthreads();
  const float* xb = x + pl * 9216;
  const u16* cb = OutC + pl * 9216;
  const u16* wb = OutW + pl * 9216;
  float* ob = out + pl * 9216;
  for (int ch = tid; ch < 2304; ch += 256) {
    int i4 = ch * 4;
    int h = i4 / 96, w = i4 % 96;
    f32x4 xv = *(const f32x4*)&xb[i4];
    us4 cv = *(const us4*)&cb[i4];
    us4 wv = *(const us4*)&wb[i4];
    f32x4 o;
#pragma unroll
    for (int e = 0; e < 4; e++)
      o[e] = xv[e] + b2f(cv[e]) + b2f(wv[e]) + b2f(T[w + e][h]);
    *(f32x4*)&ob[i4] = o;
  }
}

extern "C" void kernel_launch(void* const* d_in, const int* in_sizes, int n_in,
                              void* d_out, int out_size, void* d_ws, size_t ws_size,
                              hipStream_t stream) {
  const float* x     = (const float*)d_in[0];
  const float* w_h   = (const float*)d_in[1];
  const float* b_h   = (const float*)d_in[2];
  const float* w_w   = (const float*)d_in[3];
  const float* b_w   = (const float*)d_in[4];
  const float* w_c   = (const float*)d_in[5];
  const float* b_c   = (const float*)d_in[6];
  const float* w_o   = (const float*)d_in[7];
  const float* b_o   = (const float*)d_in[8];
  const float* alpha = (const float*)d_in[9];
  const float* beta  = (const float*)d_in[10];
  const float* gamma = (const float*)d_in[11];
  float* out = (float*)d_out;

  // Region plan. R = 37748736 (one [B][512][9216] bf16 buffer).
  //  A [0,R):   xbfT (1-4) / gram partials 33.5MB (6-7) / f_chaT (13-14) / OutW (15-16)
  //  B [R,2R):  f_ch (4-9) / OutC (9-16)
  //  C [2R,3R): f_chT (5-9) / HT (14-16)
  //  D [3R,4R): f_cha (4-15)
  //  E: fhw bf16 [B][16][9216] (3-11)
  //  F: gramN(4.19M,7-8)+affT(2.10M,8-9) overlaid by ccat 14.16M (10-15); wco after ccat (2-4)
  const size_t R = 37748736;
  char* p = (char*)d_ws;
  u16*   xbfT   = (u16*)(p);
  float* part   = (float*)(p);
  u16*   f_chaT = (u16*)(p);
  u16*   outW   = (u16*)(p);
  u16*   f_ch   = (u16*)(p + R);
  u16*   outC   = (u16*)(p + R);
  u16*   f_chT  = (u16*)(p + 2 * R);
  u16*   outHT  = (u16*)(p + 2 * R);
  u16*   f_cha  = (u16*)(p + 3 * R);
  u16*   fhw    = (u16*)(p + 4 * R);
  char*  F      = p + 4 * R + 2359296;
  float* gramN  = (float*)F;
  u16*   affT   = (u16*)(F + 4194304);
  u16*   ccat   = (u16*)F;
  u16*   wco    = (u16*)(F + 14155776);

  k_cvt_T<<<dim3(144, 8, 4), 256, 0, stream>>>(x, xbfT, 512, 9216);
  k_cvtw<<<512, 256, 0, stream>>>(w_c, w_o, wco);
  k_conv16<<<dim3(72, 4), 256, 0, stream>>>(w_h, b_h, w_w, b_w, xbfT, fhw);
  k_gemm_conv2<<<dim3(72, 8, 4), 256, 0, stream>>>(wco, xbfT, b_c, b_o, f_ch, f_cha);
  k_trT_bf<<<dim3(144, 8, 4), 256, 0, stream>>>(f_ch, f_chT, 512, 9216);
  k_gram_sk<<<dim3(4, 4, 32), 256, 0, stream>>>(f_ch, part);
  k_softmax512r<<<2048, 256, 0, stream>>>(part, gramN);
  k_cvt_T<<<dim3(8, 8, 4), 256, 0, stream>>>(gramN, affT, 512, 512);
  k_outc<<<dim3(4, 72, 4), 256, 0, stream>>>(f_chT, affT, gamma, outC);
  k_eh<<<384, 256, 0, stream>>>(fhw, ccat);
  k_ew<<<384, 256, 0, stream>>>(fhw, ccat);
  k_softmax192<<<9216, 256, 0, stream>>>(ccat);
  k_tr_plane<<<2048, 256, 0, stream>>>(f_cha, f_chaT);
  k_final_h<<<384, 512, 0, stream>>>(f_chaT, ccat, alpha, outHT);
  k_final_w<<<384, 512, 0, stream>>>(f_cha, ccat, beta, outW);
  k_merge<<<2048, 256, 0, stream>>>(x, outC, outW, outHT, out);
}

// Round 6
// 304.856 us; speedup vs baseline: 9.0492x; 1.0193x over previous
//
#include <hip/hip_runtime.h>

typedef __attribute__((ext_vector_type(8))) short short8;
typedef __attribute__((ext_vector_type(4))) float f32x4;
typedef __attribute__((ext_vector_type(4))) unsigned short us4;
typedef unsigned short u16;

#define kB 4
#define kC 512
#define kCr 8
#define kH 96
#define kW 96
#define kHW 9216
#define kCHW 4718592
#define NEGV -1e9f

__device__ __forceinline__ u16 f2b(float f) {
  union { float f; unsigned u; } v; v.f = f;
  unsigned r = v.u + 0x7fff + ((v.u >> 16) & 1);
  return (u16)(r >> 16);
}
__device__ __forceinline__ float b2f(u16 h) {
  union { unsigned u; float f; } v; v.u = ((unsigned)h) << 16;
  return v.f;
}
#define MFMA(a, b, c) __builtin_amdgcn_mfma_f32_16x16x32_bf16(a, b, c, 0, 0, 0)

// async global->LDS, 16B per lane. LDS dest must be wave-uniform-base + lane*16.
__device__ __forceinline__ void gl16(const u16* g, u16* l) {
  __builtin_amdgcn_global_load_lds(
      (const __attribute__((address_space(1))) void*)g,
      (__attribute__((address_space(3))) void*)l, 16, 0, 0);
}

// ---------- fp32 [R][C] -> bf16 [C][R] transpose-convert, 64x64 tiles ----------
__global__ __launch_bounds__(256) void k_cvt_T(const float* __restrict__ in,
                                               u16* __restrict__ out,
                                               int R, int C) {
  const float* ib = in + (size_t)blockIdx.z * R * C;
  u16* ob = out + (size_t)blockIdx.z * R * C;
  int c0 = blockIdx.x * 64, r0 = blockIdx.y * 64;
  __shared__ u16 T[64][68];
  int tid = threadIdx.x;
#pragma unroll
  for (int p = 0; p < 4; p++) {
    int ch = tid + p * 256;
    int i = ch >> 4, seg = ch & 15;
    f32x4 v = *(const f32x4*)&ib[(size_t)(r0 + i) * C + c0 + seg * 4];
    T[i][seg*4+0] = f2b(v[0]); T[i][seg*4+1] = f2b(v[1]);
    T[i][seg*4+2] = f2b(v[2]); T[i][seg*4+3] = f2b(v[3]);
  }
  __syncthreads();
#pragma unroll
  for (int p = 0; p < 4; p++) {
    int ch = tid + p * 256;
    int j = ch >> 4, seg = ch & 15;
    us4 o;
#pragma unroll
    for (int e = 0; e < 4; e++) o[e] = T[seg*4+e][j];
    *(us4*)&ob[(size_t)(c0 + j) * R + r0 + seg * 4] = o;
  }
}

// ---------- bf16 [R][C] -> bf16 [C][R] transpose, 64x64 tiles ----------
__global__ __launch_bounds__(256) void k_trT_bf(const u16* __restrict__ in,
                                                u16* __restrict__ out,
                                                int R, int C) {
  const u16* ib = in + (size_t)blockIdx.z * R * C;
  u16* ob = out + (size_t)blockIdx.z * R * C;
  int c0 = blockIdx.x * 64, r0 = blockIdx.y * 64;
  __shared__ u16 T[64][68];
  int tid = threadIdx.x;
#pragma unroll
  for (int p = 0; p < 4; p++) {
    int ch = tid + p * 256;
    int i = ch >> 4, seg = ch & 15;
    us4 v = *(const us4*)&ib[(size_t)(r0 + i) * C + c0 + seg * 4];
    T[i][seg*4+0] = v[0]; T[i][seg*4+1] = v[1];
    T[i][seg*4+2] = v[2]; T[i][seg*4+3] = v[3];
  }
  __syncthreads();
#pragma unroll
  for (int p = 0; p < 4; p++) {
    int ch = tid + p * 256;
    int j = ch >> 4, seg = ch & 15;
    us4 o;
#pragma unroll
    for (int e = 0; e < 4; e++) o[e] = T[seg*4+e][j];
    *(us4*)&ob[(size_t)(c0 + j) * R + r0 + seg * 4] = o;
  }
}

// ---------- weights fp32 -> bf16: wco[0:512]=w_c, wco[512:1024]=w_o ----------
__global__ __launch_bounds__(256) void k_cvtw(const float* __restrict__ wc,
                                              const float* __restrict__ wo,
                                              u16* __restrict__ wco) {
  int i = blockIdx.x * 256 + threadIdx.x;   // 131072 chunks of 4 floats
  const float* src = (i < 65536) ? &wc[(size_t)i * 4] : &wo[(size_t)(i - 65536) * 4];
  f32x4 v = *(const f32x4*)src;
  us4 o;
  o[0] = f2b(v[0]); o[1] = f2b(v[1]); o[2] = f2b(v[2]); o[3] = f2b(v[3]);
  ((us4*)wco)[i] = o;
}

// ---------- small convs via MFMA: fhw[b][r][hw], r<8: w_h conv, r>=8: w_w conv ----------
__global__ __launch_bounds__(256) void k_conv16(
    const float* __restrict__ wh, const float* __restrict__ bh,
    const float* __restrict__ ww, const float* __restrict__ bw,
    const u16* __restrict__ XT, u16* __restrict__ Out) {
  __shared__ u16 As[16][520];
  __shared__ float bias_s[16];
  int tid = threadIdx.x;
#pragma unroll
  for (int p = 0; p < 4; p++) {
    int ch = tid + p * 256;               // 1024 chunks of 8 elems
    int r = ch >> 6, seg = ch & 63;
    const float* src = (r < 8) ? &wh[r * 512 + seg * 8] : &ww[(r - 8) * 512 + seg * 8];
    f32x4 v0 = *(const f32x4*)src;
    f32x4 v1 = *(const f32x4*)(src + 4);
    short8 sv;
    sv[0]=f2b(v0[0]); sv[1]=f2b(v0[1]); sv[2]=f2b(v0[2]); sv[3]=f2b(v0[3]);
    sv[4]=f2b(v1[0]); sv[5]=f2b(v1[1]); sv[6]=f2b(v1[2]); sv[7]=f2b(v1[3]);
    *(short8*)&As[r][seg * 8] = sv;
  }
  if (tid < 16) bias_s[tid] = (tid < 8) ? bh[tid] : bw[tid - 8];
  __syncthreads();
  int b = blockIdx.y;
  int nb = blockIdx.x * 128 + (tid >> 6) * 32;   // wave's 32-n strip
  int lane = tid & 63;
  int lr = lane & 15, lg = lane >> 4;
  const u16* Bb = XT + (size_t)b * kCHW;
  f32x4 acc[2] = {};
#pragma unroll 4
  for (int k0 = 0; k0 < 512; k0 += 32) {
    short8 a = *(const short8*)&As[lr][k0 + lg * 8];
    short8 b0 = *(const short8*)&Bb[(size_t)(nb + lr) * 512 + k0 + lg * 8];
    short8 b1 = *(const short8*)&Bb[(size_t)(nb + 16 + lr) * 512 + k0 + lg * 8];
    acc[0] = MFMA(a, b0, acc[0]);
    acc[1] = MFMA(a, b1, acc[1]);
  }
#pragma unroll
  for (int q = 0; q < 2; q++)
#pragma unroll
    for (int r = 0; r < 4; r++) {
      int m = lg * 4 + r;
      Out[((size_t)b * 16 + m) * kHW + nb + q * 16 + lr] = f2b(acc[q][r] + bias_s[m]);
    }
}

// ======== shared pipelined 128x128 GEMM body (A.B^T, K-major rows) ========
// LDS linear [2][128][64], gload_lds staging, XOR chunk-swizzle both sides.
// Counted-vmcnt schedule (T3+T4 lite): loads for tile t+1 stay in flight across
// the barrier; vmcnt never drained to 0 inside the loop.
#define GEMM_PROLOG()                                                      \
  int tid = threadIdx.x;                                                   \
  int lane = tid & 63, wv = tid >> 6;                                      \
  int wr = (wv >> 1) * 64, wc = (wv & 1) * 64;                             \
  int lr = lane & 15, lg = lane >> 4;                                      \
  f32x4 acc[4][4] = {};

#define STAGE(bufv, kk)                                                    \
  {                                                                        \
    _Pragma("unroll")                                                      \
    for (int p = 0; p < 4; p++) {                                          \
      int ch = tid + p * 256;                                              \
      int row = ch >> 3, cc = ch & 7;                                      \
      int sc = (cc ^ (row & 7)) * 8;                                       \
      gl16(&Asrc[(size_t)(bm + row) * LDA + (kk) + sc], &As[bufv][row][cc * 8]); \
      gl16(&Bsrc[(size_t)(bn + row) * LDB + (kk) + sc], &Bs[bufv][row][cc * 8]); \
    }                                                                      \
  }

#define COMPUTE(bufv)                                                      \
  {                                                                        \
    _Pragma("unroll")                                                      \
    for (int ks = 0; ks < 2; ks++) {                                       \
      int ca = ((ks * 4 + lg) ^ (lr & 7)) * 8;                             \
      short8 av[4], bv[4];                                                 \
      _Pragma("unroll")                                                    \
      for (int m = 0; m < 4; m++)                                          \
        av[m] = *(const short8*)&As[bufv][wr + m * 16 + lr][ca];           \
      _Pragma("unroll")                                                    \
      for (int n = 0; n < 4; n++)                                          \
        bv[n] = *(const short8*)&Bs[bufv][wc + n * 16 + lr][ca];           \
      __builtin_amdgcn_s_setprio(1);                                       \
      _Pragma("unroll")                                                    \
      for (int m = 0; m < 4; m++)                                          \
        _Pragma("unroll")                                                  \
        for (int n = 0; n < 4; n++)                                        \
          acc[m][n] = MFMA(av[m], bv[n], acc[m][n]);                       \
      __builtin_amdgcn_s_setprio(0);                                       \
    }                                                                      \
  }

#define VMBAR(N)                                                           \
  asm volatile("s_waitcnt vmcnt(" #N ")" ::: "memory");                    \
  __builtin_amdgcn_s_barrier();

#define LGBAR                                                              \
  asm volatile("s_waitcnt lgkmcnt(0)" ::: "memory");                       \
  __builtin_amdgcn_s_barrier();

// NT K-tiles of 64 starting at KBASE. Requires NT >= 2.
#define PIPELOOP(NT, KBASE)                                                \
  STAGE(0, (KBASE));                                                       \
  STAGE(1, (KBASE) + 64);                                                  \
  {                                                                        \
    int cur = 0;                                                           \
    _Pragma("unroll 1")                                                    \
    for (int t = 0; t < (NT) - 2; t++) {                                   \
      VMBAR(8);                                                            \
      COMPUTE(cur);                                                        \
      LGBAR;                                                               \
      STAGE(cur, (KBASE) + (t + 2) * 64);                                  \
      cur ^= 1;                                                            \
    }                                                                      \
    VMBAR(8);                                                              \
    COMPUTE(cur);                                                          \
    cur ^= 1;                                                              \
    VMBAR(0);                                                              \
    COMPUTE(cur);                                                          \
  }

// ---------- merged conv1x1 GEMM: M=1024 (w_c rows then w_o rows) ----------
__global__ __launch_bounds__(256) void k_gemm_conv2(
    const u16* __restrict__ wco, const u16* __restrict__ BT,
    const float* __restrict__ b_c, const float* __restrict__ b_o,
    u16* __restrict__ f_ch, u16* __restrict__ f_cha) {
  __shared__ u16 As[2][128][64];
  __shared__ u16 Bs[2][128][64];
  int b = blockIdx.z;
  int bm = blockIdx.y * 128;   // o in [0,1024)
  int bn = blockIdx.x * 128;   // hw
  const u16* Asrc = wco;
  const u16* Bsrc = BT + (size_t)b * kCHW;
  const int LDA = 512, LDB = 512;
  GEMM_PROLOG();
  PIPELOOP(8, 0);
  const float* biasp = (bm < 512) ? (b_c + bm) : (b_o + bm - 512);
  u16* Ob = (bm < 512) ? (f_ch + (size_t)b * kCHW + (size_t)bm * kHW)
                       : (f_cha + (size_t)b * kCHW + (size_t)(bm - 512) * kHW);
#pragma unroll
  for (int m = 0; m < 4; m++)
#pragma unroll
    for (int r = 0; r < 4; r++) {
      int ol = wr + m * 16 + lg * 4 + r;
      float bv_ = biasp[ol];
#pragma unroll
      for (int n = 0; n < 4; n++)
        Ob[(size_t)ol * kHW + bn + wc + n * 16 + lr] = f2b(acc[m][n][r] + bv_);
    }
}

// ---------- Gram split-K (pipelined): part bf16 [s*4+b][i][j] ----------
__global__ __launch_bounds__(256) void k_gram_sk(const u16* __restrict__ F,
                                                 u16* __restrict__ part) {
  __shared__ u16 As[2][128][64];
  __shared__ u16 Bs[2][128][64];
  int z = blockIdx.z;
  int b = z & 3, s = z >> 2;
  int bm = blockIdx.y * 128, bn = blockIdx.x * 128;
  const u16* Asrc = F + (size_t)b * kCHW;
  const u16* Bsrc = Asrc;
  const int LDA = kHW, LDB = kHW;
  int kbeg = s * 1152;
  GEMM_PROLOG();
  PIPELOOP(18, kbeg);
  u16* Pb = part + ((size_t)(s * 4 + b)) * 262144;
#pragma unroll
  for (int m = 0; m < 4; m++)
#pragma unroll
    for (int r = 0; r < 4; r++) {
      int i = bm + wr + m * 16 + lg * 4 + r;
#pragma unroll
      for (int n = 0; n < 4; n++)
        Pb[(size_t)i * 512 + bn + wc + n * 16 + lr] = f2b(acc[m][n][r]);
    }
}

// ---------- out_C GEMM (pipelined) -> bf16 OutC[b][hw][c] (flat == d_out) ----------
__global__ __launch_bounds__(256) void k_outc(
    const u16* __restrict__ AT, const u16* __restrict__ Bt,
    const float* __restrict__ gamma, u16* __restrict__ Out) {
  __shared__ u16 As[2][128][64];
  __shared__ u16 Bs[2][128][64];
  int b = blockIdx.z;
  int bm = blockIdx.y * 128;   // hw
  int bn = blockIdx.x * 128;   // c
  const u16* Asrc = AT + (size_t)b * kCHW;
  const u16* Bsrc = Bt + (size_t)b * 262144;
  const int LDA = 512, LDB = 512;
  GEMM_PROLOG();
  PIPELOOP(8, 0);
  float g = *gamma;
  u16* Ob = Out + (size_t)b * kCHW;
#pragma unroll
  for (int m = 0; m < 4; m++)
#pragma unroll
    for (int r = 0; r < 4; r++) {
      int mm = bm + wr + m * 16 + lg * 4 + r;
#pragma unroll
      for (int n = 0; n < 4; n++)
        Ob[(size_t)mm * 512 + bn + wc + n * 16 + lr] = f2b(g * acc[m][n][r]);
    }
}

// ---------- 8-way bf16 partial reduce + row softmax over 512 -> gramN fp32 ----------
__global__ __launch_bounds__(256) void k_softmax512r(const u16* __restrict__ part,
                                                     float* __restrict__ gramN) {
  int b = blockIdx.x >> 9, i = blockIdx.x & 511;
  int tid = threadIdx.x;
  float v0 = 0.f, v1 = 0.f;
#pragma unroll
  for (int s = 0; s < 8; s++) {
    const u16* P = part + ((size_t)(s * 4 + b) * 512 + i) * 512;
    v0 += b2f(P[tid]);
    v1 += b2f(P[tid + 256]);
  }
  int wid = tid >> 6, lane = tid & 63;
  float m = fmaxf(v0, v1);
#pragma unroll
  for (int o = 32; o >= 1; o >>= 1) m = fmaxf(m, __shfl_xor(m, o));
  __shared__ float redm[4], reds[4];
  if (lane == 0) redm[wid] = m;
  __syncthreads();
  m = fmaxf(fmaxf(redm[0], redm[1]), fmaxf(redm[2], redm[3]));
  float e0 = expf(v0 - m), e1 = expf(v1 - m);
  float s = e0 + e1;
#pragma unroll
  for (int o = 32; o >= 1; o >>= 1) s += __shfl_xor(s, o);
  if (lane == 0) reds[wid] = s;
  __syncthreads();
  s = reds[0] + reds[1] + reds[2] + reds[3];
  float inv = 1.0f / s;
  float* R = gramN + ((size_t)b * 512 + i) * 512;
  R[tid] = e0 * inv;
  R[tid + 256] = e1 * inv;
}

// ---------- E_h -> ccat[b,i,w, j<96] (bf16 in/out) ----------
__global__ __launch_bounds__(256) void k_eh(
    const u16* __restrict__ fhw, u16* __restrict__ Ccat) {
  int b = blockIdx.x / kW, w = blockIdx.x % kW;
  __shared__ float fh[kH][kCr];
  __shared__ float fw[kCr][kH];
  int tid = threadIdx.x;
  for (int l = tid; l < kH * kCr; l += 256) {
    int i = l >> 3, c = l & 7;
    fh[i][c] = b2f(fhw[((size_t)b * 16 + (i & 7)) * kHW + (c * 12 + (i >> 3)) * kW + w]);
    int c2 = l / kH, j = l % kH;
    fw[c2][j] = b2f(fhw[((size_t)b * 16 + 8 + c2) * kHW + j * kW + w]);
  }
  __syncthreads();
  for (int t = tid; t < kH * kH; t += 256) {
    int i = t / kH, j = t % kH;
    float e = 0.f;
#pragma unroll
    for (int c = 0; c < kCr; c++) e += fh[i][c] * fw[c][j];
    if (i == j) e += NEGV;
    Ccat[(((size_t)b * kH + i) * kW + w) * 192 + j] = f2b(e);
  }
}

// ---------- E_w -> ccat[b,h,w, 96+j] (bf16 in/out) ----------
__global__ __launch_bounds__(256) void k_ew(
    const u16* __restrict__ fhw, u16* __restrict__ Ccat) {
  int b = blockIdx.x / kH, h = blockIdx.x % kH;
  __shared__ float fh2[kCr][kW];
  __shared__ float fw2[kCr][kW];
  int tid = threadIdx.x;
  for (int l = tid; l < kCr * kW; l += 256) {
    int c = l / kW, w = l % kW;
    fh2[c][w] = b2f(fhw[((size_t)b * 16 + c) * kHW + h * kW + w]);
    fw2[c][w] = b2f(fhw[((size_t)b * 16 + 8 + c) * kHW + h * kW + w]);
  }
  __syncthreads();
  for (int t = tid; t < kW * kW; t += 256) {
    int w = t / kW, j = t % kW;
    float e = 0.f;
#pragma unroll
    for (int c = 0; c < kCr; c++) e += fh2[c][w] * fw2[c][j];
    Ccat[(((size_t)b * kH + h) * kW + w) * 192 + 96 + j] = f2b(e);
  }
}

// ---------- softmax over 192 (bf16 in-place), one wave per row ----------
__global__ __launch_bounds__(256) void k_softmax192(u16* __restrict__ Ccat) {
  int r = blockIdx.x * 4 + (threadIdx.x >> 6);
  int lane = threadIdx.x & 63;
  u16* R = Ccat + (size_t)r * 192;
  float a = b2f(R[lane]), b = b2f(R[lane + 64]), c = b2f(R[lane + 128]);
  float m = fmaxf(a, fmaxf(b, c));
#pragma unroll
  for (int o = 32; o >= 1; o >>= 1) m = fmaxf(m, __shfl_xor(m, o));
  float ea = expf(a - m), eb = expf(b - m), ec = expf(c - m);
  float s = ea + eb + ec;
#pragma unroll
  for (int o = 32; o >= 1; o >>= 1) s += __shfl_xor(s, o);
  float inv = 1.0f / s;
  R[lane] = f2b(ea * inv);
  R[lane + 64] = f2b(eb * inv);
  R[lane + 128] = f2b(ec * inv);
}

// ---------- per-(b,c) 96x96 plane transpose (bf16) ----------
__global__ __launch_bounds__(256) void k_tr_plane(const u16* __restrict__ in,
                                                  u16* __restrict__ out) {
  size_t pl = blockIdx.x;
  const u16* ib = in + pl * 9216;
  u16* ob = out + pl * 9216;
  __shared__ u16 T[96][100];
  int tid = threadIdx.x;
  for (int ch = tid; ch < 96 * 24; ch += 256) {
    int i = ch / 24, seg = ch % 24;
    *(us4*)&T[i][seg*4] = *(const us4*)&ib[i*96 + seg*4];
  }
  __syncthreads();
  for (int ch = tid; ch < 96 * 24; ch += 256) {
    int j = ch / 24, seg = ch % 24;
    us4 o;
#pragma unroll
    for (int e = 0; e < 4; e++) o[e] = T[seg*4+e][j];
    *(us4*)&ob[j*96 + seg*4] = o;
  }
}

// ---------- H-path: per (b,w): HT[b][c][w][h] = alpha * sum_j AT[c][j] att[h][j] ----------
__global__ __launch_bounds__(512) void k_final_h(
    const u16* __restrict__ AT,    // f_chaT [B][512][96(w)][96(j=h)]
    const u16* __restrict__ att,   // ccat bf16 [B][96][96][192]
    const float* __restrict__ alpha,
    u16* __restrict__ OutHT) {
  int b = blockIdx.x / 96, w = blockIdx.x % 96;
  __shared__ u16 Bs[96][104];
  int tid = threadIdx.x;
  for (int ch = tid; ch < 1152; ch += 512) {
    int h = ch / 12, seg = ch % 12;
    *(short8*)&Bs[h][seg*8] =
        *(const short8*)&att[(((size_t)b*96 + h)*96 + w)*192 + seg*8];
  }
  __syncthreads();
  int lane = tid & 63, wv = tid >> 6;
  int lr = lane & 15, lg = lane >> 4;
  int c0 = wv * 64;
  const u16* Ab = AT + ((size_t)b*512 + c0)*kHW + w*96;
  f32x4 acc[4][6] = {};
#pragma unroll
  for (int ks = 0; ks < 3; ks++) {
    short8 av[4];
#pragma unroll
    for (int m = 0; m < 4; m++)
      av[m] = *(const short8*)&Ab[(size_t)(m*16 + lr)*kHW + ks*32 + lg*8];
#pragma unroll
    for (int n = 0; n < 6; n++) {
      short8 bv = *(const short8*)&Bs[n*16 + lr][ks*32 + lg*8];
#pragma unroll
      for (int m = 0; m < 4; m++) acc[m][n] = MFMA(av[m], bv, acc[m][n]);
    }
  }
  float al = *alpha;
  u16* Ob = OutHT + ((size_t)b*512 + c0)*kHW + w*96;
#pragma unroll
  for (int m = 0; m < 4; m++)
#pragma unroll
    for (int r = 0; r < 4; r++) {
      size_t crow = (size_t)(m*16 + lg*4 + r) * kHW;
#pragma unroll
      for (int n = 0; n < 6; n++)
        Ob[crow + n*16 + lr] = f2b(al * acc[m][n][r]);
    }
}

// ---------- W-path: per (b,h): OutW[b][c][h][w] = beta * sum_j A[c][j] att[w][96+j] ----------
__global__ __launch_bounds__(512) void k_final_w(
    const u16* __restrict__ A,     // f_cha [B][512][96(h)][96(j=w)]
    const u16* __restrict__ att,
    const float* __restrict__ beta,
    u16* __restrict__ OutW) {
  int b = blockIdx.x / 96, h = blockIdx.x % 96;
  __shared__ u16 Bs[96][104];
  int tid = threadIdx.x;
  for (int ch = tid; ch < 1152; ch += 512) {
    int wr_ = ch / 12, seg = ch % 12;
    *(short8*)&Bs[wr_][seg*8] =
        *(const short8*)&att[(((size_t)b*96 + h)*96 + wr_)*192 + 96 + seg*8];
  }
  __syncthreads();
  int lane = tid & 63, wv = tid >> 6;
  int lr = lane & 15, lg = lane >> 4;
  int c0 = wv * 64;
  const u16* Ab = A + ((size_t)b*512 + c0)*kHW + h*96;
  f32x4 acc[4][6] = {};
#pragma unroll
  for (int ks = 0; ks < 3; ks++) {
    short8 av[4];
#pragma unroll
    for (int m = 0; m < 4; m++)
      av[m] = *(const short8*)&Ab[(size_t)(m*16 + lr)*kHW + ks*32 + lg*8];
#pragma unroll
    for (int n = 0; n < 6; n++) {
      short8 bv = *(const short8*)&Bs[n*16 + lr][ks*32 + lg*8];
#pragma unroll
      for (int m = 0; m < 4; m++) acc[m][n] = MFMA(av[m], bv, acc[m][n]);
    }
  }
  float be = *beta;
  u16* Ob = OutW + ((size_t)b*512 + c0)*kHW + h*96;
#pragma unroll
  for (int m = 0; m < 4; m++)
#pragma unroll
    for (int r = 0; r < 4; r++) {
      size_t crow = (size_t)(m*16 + lg*4 + r) * kHW;
#pragma unroll
      for (int n = 0; n < 6; n++)
        Ob[crow + n*16 + lr] = f2b(be * acc[m][n][r]);
    }
}

// ---------- merge: out = x + OutC + OutW + HT^T(per plane) ----------
__global__ __launch_bounds__(256) void k_merge(
    const float* __restrict__ x, const u16* __restrict__ OutC,
    const u16* __restrict__ OutW, const u16* __restrict__ HT,
    float* __restrict__ out) {
  size_t pl = blockIdx.x;
  const u16* hb = HT + pl * 9216;
  __shared__ u16 T[96][100];
  int tid = threadIdx.x;
  for (int ch = tid; ch < 96 * 24; ch += 256) {
    int i = ch / 24, seg = ch % 24;
    *(us4*)&T[i][seg*4] = *(const us4*)&hb[i*96 + seg*4];
  }
  __syncthreads();
  const float* xb = x + pl * 9216;
  const u16* cb = OutC + pl * 9216;
  const u16* wb = OutW + pl * 9216;
  float* ob = out + pl * 9216;
  for (int ch = tid; ch < 2304; ch += 256) {
    int i4 = ch * 4;
    int h = i4 / 96, w = i4 % 96;
    f32x4 xv = *(const f32x4*)&xb[i4];
    us4 cv = *(const us4*)&cb[i4];
    us4 wv = *(const us4*)&wb[i4];
    f32x4 o;
#pragma unroll
    for (int e = 0; e < 4; e++)
      o[e] = xv[e] + b2f(cv[e]) + b2f(wv[e]) + b2f(T[w + e][h]);
    *(f32x4*)&ob[i4] = o;
  }
}

extern "C" void kernel_launch(void* const* d_in, const int* in_sizes, int n_in,
                              void* d_out, int out_size, void* d_ws, size_t ws_size,
                              hipStream_t stream) {
  const float* x     = (const float*)d_in[0];
  const float* w_h   = (const float*)d_in[1];
  const float* b_h   = (const float*)d_in[2];
  const float* w_w   = (const float*)d_in[3];
  const float* b_w   = (const float*)d_in[4];
  const float* w_c   = (const float*)d_in[5];
  const float* b_c   = (const float*)d_in[6];
  const float* w_o   = (const float*)d_in[7];
  const float* b_o   = (const float*)d_in[8];
  const float* alpha = (const float*)d_in[9];
  const float* beta  = (const float*)d_in[10];
  const float* gamma = (const float*)d_in[11];
  float* out = (float*)d_out;

  // Region plan. R = 37748736 (one [B][512][9216] bf16 buffer).
  //  A [0,R):   xbfT (1-4) / gram partials bf16 16.8MB (6-7) / f_chaT (13-14) / OutW (15-16)
  //  B [R,2R):  f_ch (4-9) / OutC (9-16)
  //  C [2R,3R): f_chT (5-9) / HT (14-16)
  //  D [3R,4R): f_cha (4-15)
  //  E: fhw bf16 [B][16][9216] (3-11)
  //  F: gramN(4.19M,7-8)+affT(2.10M,8-9) overlaid by ccat 14.16M (10-15); wco after ccat (2-4)
  const size_t R = 37748736;
  char* p = (char*)d_ws;
  u16*   xbfT   = (u16*)(p);
  u16*   part   = (u16*)(p);
  u16*   f_chaT = (u16*)(p);
  u16*   outW   = (u16*)(p);
  u16*   f_ch   = (u16*)(p + R);
  u16*   outC   = (u16*)(p + R);
  u16*   f_chT  = (u16*)(p + 2 * R);
  u16*   outHT  = (u16*)(p + 2 * R);
  u16*   f_cha  = (u16*)(p + 3 * R);
  u16*   fhw    = (u16*)(p + 4 * R);
  char*  F      = p + 4 * R + 2359296;
  float* gramN  = (float*)F;
  u16*   affT   = (u16*)(F + 4194304);
  u16*   ccat   = (u16*)F;
  u16*   wco    = (u16*)(F + 14155776);

  k_cvt_T<<<dim3(144, 8, 4), 256, 0, stream>>>(x, xbfT, 512, 9216);
  k_cvtw<<<512, 256, 0, stream>>>(w_c, w_o, wco);
  k_conv16<<<dim3(72, 4), 256, 0, stream>>>(w_h, b_h, w_w, b_w, xbfT, fhw);
  k_gemm_conv2<<<dim3(72, 8, 4), 256, 0, stream>>>(wco, xbfT, b_c, b_o, f_ch, f_cha);
  k_trT_bf<<<dim3(144, 8, 4), 256, 0, stream>>>(f_ch, f_chT, 512, 9216);
  k_gram_sk<<<dim3(4, 4, 32), 256, 0, stream>>>(f_ch, part);
  k_softmax512r<<<2048, 256, 0, stream>>>(part, gramN);
  k_cvt_T<<<dim3(8, 8, 4), 256, 0, stream>>>(gramN, affT, 512, 512);
  k_outc<<<dim3(4, 72, 4), 256, 0, stream>>>(f_chT, affT, gamma, outC);
  k_eh<<<384, 256, 0, stream>>>(fhw, ccat);
  k_ew<<<384, 256, 0, stream>>>(fhw, ccat);
  k_softmax192<<<9216, 256, 0, stream>>>(ccat);
  k_tr_plane<<<2048, 256, 0, stream>>>(f_cha, f_chaT);
  k_final_h<<<384, 512, 0, stream>>>(f_chaT, ccat, alpha, outHT);
  k_final_w<<<384, 512, 0, stream>>>(f_cha, ccat, beta, outW);
  k_merge<<<2048, 256, 0, stream>>>(x, outC, outW, outHT, out);
}